// Round 1
// baseline (583.688 us; speedup 1.0000x reference)
//
#include <hip/hip_runtime.h>
#include <hip/hip_bf16.h>
#include <math.h>

// ---------------- model constants ----------------
#define BB   64
#define TT   448
#define TTT  449
#define DIM  256
#define HEADS 8
#define HD   32
#define LAYERS 4
#define FFD  1024
#define INDIM 64
#define MPAD 28800
// dependency cone (window [qb-32, qb+47], chunk-granular):
#define TFRONT 160            // front-end rows/batch
#define MFRONT (BB*TFRONT)    // 10240
#define GROWS  168            // guarded rows/batch in h448g (8 zero + 160)

typedef __attribute__((ext_vector_type(8))) short short8;
typedef __attribute__((ext_vector_type(4))) float f32x4;
typedef unsigned short ushort_t;

__device__ __forceinline__ float gelu_f(float x) {
    float x2 = x * x;
    float m = 0.10295219f * x2 + 2.3022635f;
    float t = exp2f(-x * m);
    return x * (1.f / (1.f + t));
}
__device__ __forceinline__ ushort_t f2bf(float x) {
    unsigned u; __builtin_memcpy(&u, &x, 4);
    return (ushort_t)((u + 0x8000u) >> 16);
}
__device__ __forceinline__ unsigned pack2bf(float a, float b) {
    unsigned ua, ub;
    __builtin_memcpy(&ua, &a, 4); __builtin_memcpy(&ub, &b, 4);
    return ((ua + 0x8000u) >> 16) | ((ub + 0x8000u) & 0xffff0000u);
}
__device__ __forceinline__ float bf2f(ushort_t u) {
    unsigned v = ((unsigned)u) << 16; float f; __builtin_memcpy(&f, &v, 4); return f;
}
__device__ __forceinline__ void gload16(const ushort_t* g, ushort_t* l) {
    __builtin_amdgcn_global_load_lds(
        (const __attribute__((address_space(1))) void*)g,
        (__attribute__((address_space(3))) void*)l, 16, 0, 0);
}

// ---------------- bf16 MFMA GEMM v7 (R12 structure) ----------------
// C[m,n] = sum_k A[m,k] * Bt[n,k]
// a_dil > 0 : conv mode — A is guard-padded h448g [b*168 + 8 + t], t=gm%160.
// a_dil == -1: merged conv (blockIdx.z selects scale s: a_dil=1<<s).
// a_dil == -2: A is f32 x [b*448 + t] (t=gm%160); C2 written to h448g layout.
// rc_mod > 0: R and C row = (gm/rc_mod)*449 + gm%rc_mod (h449 layout).
// pe_mode: C row = (gm/160)*449 + 1 + gm%160, add sinusoidal PE (f32 out).
__global__ __launch_bounds__(256, 3) void gemm_bf16(
    const ushort_t* __restrict__ A, const ushort_t* __restrict__ Bt,
    void* __restrict__ C, ushort_t* __restrict__ C2,
    const float* __restrict__ bias,
    const float* __restrict__ scalev, const float* __restrict__ shiftv,
    const float* __restrict__ R,
    int M, int N, int K, int a_dil, int do_gelu, int out_mode, int pe_mode,
    int rc_mod)
{
    __shared__ ushort_t smem[2 * 128 * 64];
    ushort_t* As = smem;
    ushort_t* Bs = smem + 128 * 64;
    const int tid = threadIdx.x;
    const int lane = tid & 63, w = tid >> 6;
    const int wm = w >> 1, wn = w & 1;
    const int l15 = lane & 15, quad = lane >> 4;
    const int m0 = blockIdx.y * 128, n0 = blockIdx.x * 128;
    const int sr = lane >> 3, ss = lane & 7;
    const int gsw = ss ^ sr;

    if (a_dil == -1) {                 // merged conv dispatch
        int z = blockIdx.z;
        a_dil = 1 << z;
        Bt += (size_t)z * 196608;
        C = (void*)((ushort_t*)C + (size_t)z * MFRONT * 256);
        bias += z * 256; scalev += z * 256; shiftv += z * 256;
    }
    const ushort_t* aconv[4];
    if (a_dil > 0) {
        #pragma unroll
        for (int j = 0; j < 4; ++j) {
            int r = (w * 4 + j) * 8 + sr;
            int gm = m0 + r;
            int b = gm / TFRONT, t = gm - b * TFRONT;
            aconv[j] = A + ((size_t)(b * GROWS + 8 + t)) * 256 + gsw * 8;
        }
    }
    f32x4 acc[4][4] = {};

    for (int k0 = 0; k0 < K; k0 += 64) {
        if (a_dil > 0) {
            int tap = k0 >> 8;
            int aoff = (k0 & 255) - ((2 - tap) * a_dil) * 256;
            #pragma unroll
            for (int j = 0; j < 4; ++j)
                gload16(aconv[j] + aoff, &As[(w * 4 + j) * 512]);
        } else if (a_dil == -2) {
            const float* Af = (const float*)A;
            #pragma unroll
            for (int j = 0; j < 4; ++j) {
                int r = (w * 4 + j) * 8 + sr;
                int gm = m0 + r;
                int b = gm / TFRONT, t = gm - b * TFRONT;
                const float* ap = Af + ((size_t)b * 448 + t) * K + k0 + gsw * 8;
                float4 a0 = *(const float4*)ap;
                float4 a1 = *(const float4*)(ap + 4);
                uint2 lo = make_uint2(pack2bf(a0.x, a0.y), pack2bf(a0.z, a0.w));
                uint2 hi = make_uint2(pack2bf(a1.x, a1.y), pack2bf(a1.z, a1.w));
                *(uint2*)&As[r * 64 + ss * 8] = lo;
                *(uint2*)&As[r * 64 + ss * 8 + 4] = hi;
            }
        } else {
            #pragma unroll
            for (int j = 0; j < 4; ++j) {
                int r = (w * 4 + j) * 8 + sr;
                int g = ss ^ (r & 7);
                gload16(&A[(size_t)(m0 + r) * K + k0 + g * 8], &As[(w * 4 + j) * 512]);
            }
        }
        #pragma unroll
        for (int j = 0; j < 4; ++j) {
            int r = (w * 4 + j) * 8 + sr;
            int g = ss ^ (r & 7);
            gload16(&Bt[(size_t)(n0 + r) * K + k0 + g * 8], &Bs[(w * 4 + j) * 512]);
        }
        __syncthreads();
        #pragma unroll
        for (int ks = 0; ks < 2; ++ks) {
            short8 af[4], bfr[4];
            #pragma unroll
            for (int i = 0; i < 4; ++i) {
                int row = wm * 64 + i * 16 + l15;
                af[i] = *(const short8*)&As[row * 64 + (((ks * 4 + quad) ^ (l15 & 7)) * 8)];
            }
            #pragma unroll
            for (int j = 0; j < 4; ++j) {
                int row = wn * 64 + j * 16 + l15;
                bfr[j] = *(const short8*)&Bs[row * 64 + (((ks * 4 + quad) ^ (l15 & 7)) * 8)];
            }
            #pragma unroll
            for (int i = 0; i < 4; ++i)
                #pragma unroll
                for (int j = 0; j < 4; ++j)
                    acc[i][j] = __builtin_amdgcn_mfma_f32_16x16x32_bf16(
                        af[i], bfr[j], acc[i][j], 0, 0, 0);
        }
        __syncthreads();
    }

    // ---- vectorized epilogue via per-wave LDS transpose ----
    float* wreg = (float*)smem + w * 2048;
    const int gn0 = n0 + wn * 64 + l15 * 4;
    float4 bias4 = bias ? *(const float4*)&bias[gn0] : make_float4(0.f, 0.f, 0.f, 0.f);
    float4 scl4, shf4;
    if (scalev) { scl4 = *(const float4*)&scalev[gn0]; shf4 = *(const float4*)&shiftv[gn0]; }
    else        { scl4 = make_float4(1.f, 1.f, 1.f, 1.f); shf4 = make_float4(0.f, 0.f, 0.f, 0.f); }

    #pragma unroll
    for (int ci = 0; ci < 2; ++ci) {
        #pragma unroll
        for (int i2 = 0; i2 < 2; ++i2) {
            int i = ci * 2 + i2;
            #pragma unroll
            for (int j = 0; j < 4; ++j) {
                float* col = &wreg[(i2 * 16 + quad * 4) * 64 + j * 16 + l15];
                #pragma unroll
                for (int r = 0; r < 4; ++r) col[r * 64] = acc[i][j][r];
            }
        }
        #pragma unroll
        for (int rr = 0; rr < 8; ++rr) {
            int rl = rr * 4 + quad;
            float4 v = *(float4*)&wreg[rl * 64 + l15 * 4];
            int gm = m0 + wm * 64 + ci * 32 + rl;
            v.x += bias4.x; v.y += bias4.y; v.z += bias4.z; v.w += bias4.w;
            if (do_gelu) { v.x = gelu_f(v.x); v.y = gelu_f(v.y); v.z = gelu_f(v.z); v.w = gelu_f(v.w); }
            v.x = v.x * scl4.x + shf4.x; v.y = v.y * scl4.y + shf4.y;
            v.z = v.z * scl4.z + shf4.z; v.w = v.w * scl4.w + shf4.w;
            size_t crow = (size_t)gm;
            if (rc_mod > 0) crow = (size_t)(gm / rc_mod) * 449 + (gm % rc_mod);
            if (R) {
                float4 r4 = *(const float4*)&R[crow * N + gn0];
                v.x += r4.x; v.y += r4.y; v.z += r4.z; v.w += r4.w;
            }
            if (pe_mode) {
                int bi = gm / TFRONT, t = gm - bi * TFRONT;
                float ft = (float)t;
                float f0 = __expf(-9.210340371976184f * (float)gn0 * (1.f / 256.f));
                float f1 = __expf(-9.210340371976184f * (float)(gn0 + 2) * (1.f / 256.f));
                float a0 = ft * f0, a1 = ft * f1;
                v.x += __sinf(a0); v.y += __cosf(a0);
                v.z += __sinf(a1); v.w += __cosf(a1);
                *(float4*)&((float*)C)[(size_t)(bi * 449 + 1 + t) * 256 + gn0] = v;
            } else if (out_mode == 1) {
                uint2 pk = make_uint2(pack2bf(v.x, v.y), pack2bf(v.z, v.w));
                *(uint2*)&((ushort_t*)C)[crow * N + gn0] = pk;
            } else {
                *(float4*)&((float*)C)[crow * N + gn0] = v;
                if (out_mode == 2) {
                    int bi = gm / TFRONT, t = gm - bi * TFRONT;
                    size_t grow = (size_t)(bi * GROWS + 8 + t);
                    uint2 pk = make_uint2(pack2bf(v.x, v.y), pack2bf(v.z, v.w));
                    *(uint2*)&C2[grow * N + gn0] = pk;
                }
            }
        }
    }
}

// ---------------- bf16 MFMA GEMM + fused LayerNorm (N=256 full-row tile) ----
// Tile 64x256, 4 waves (each 64 rows x 64-col slice). Epilogue:
// v = acc + bias (+R residual) (+PE) -> write C (f32, h449 layout) and
// Y = LN(v)*lng+lnb (bf16, linear rows). pe_mode: C row = b*449+1+t,
// Y row = gm+1 (skip t==159). Y==null: skip LN output (ffn2 of last layer).
__global__ __launch_bounds__(256, 3) void gemm_ln(
    const ushort_t* __restrict__ A, const ushort_t* __restrict__ Bt,
    float* __restrict__ C, ushort_t* __restrict__ Y,
    const float* __restrict__ bias, const float* __restrict__ R,
    const float* __restrict__ lng, const float* __restrict__ lnb,
    int M, int K, int pe_mode, int rc_mod)
{
    __shared__ __align__(16) char smraw[42240];
    ushort_t* As = (ushort_t*)smraw;             // 64x64 bf16   (8 KB)
    ushort_t* Bs = (ushort_t*)(smraw + 8192);    // 256x64 bf16  (32 KB)
    float* sums = (float*)(smraw + 40960);       // [32][4] partial row sums
    float* sqs  = (float*)(smraw + 41472);       // [32][4] partial row sq-sums
    float* mst  = (float*)(smraw + 41984);       // [64]: 0..31 mean, 32..63 rstd
    const int tid = threadIdx.x;
    const int lane = tid & 63, w = tid >> 6;
    const int l15 = lane & 15, quad = lane >> 4;
    const int m0 = blockIdx.y * 64;
    const int sr = lane >> 3, ss = lane & 7;
    const int gsw = ss ^ sr;

    f32x4 acc[4][4] = {};

    for (int k0 = 0; k0 < K; k0 += 64) {
        #pragma unroll
        for (int j = 0; j < 2; ++j) {            // A: 64 rows = 8 chunks
            int ch = w * 2 + j;
            gload16(&A[(size_t)(m0 + ch * 8 + sr) * K + k0 + gsw * 8], &As[ch * 512]);
        }
        #pragma unroll
        for (int j = 0; j < 8; ++j) {            // B: 256 rows = 32 chunks
            int ch = w * 8 + j;
            gload16(&Bt[(size_t)(ch * 8 + sr) * K + k0 + gsw * 8], &Bs[ch * 512]);
        }
        __syncthreads();
        #pragma unroll
        for (int ks = 0; ks < 2; ++ks) {
            short8 af[4], bfr[4];
            #pragma unroll
            for (int i = 0; i < 4; ++i) {
                int row = i * 16 + l15;
                af[i] = *(const short8*)&As[row * 64 + (((ks * 4 + quad) ^ (l15 & 7)) * 8)];
            }
            #pragma unroll
            for (int j = 0; j < 4; ++j) {
                int row = w * 64 + j * 16 + l15;
                bfr[j] = *(const short8*)&Bs[row * 64 + (((ks * 4 + quad) ^ (l15 & 7)) * 8)];
            }
            #pragma unroll
            for (int i = 0; i < 4; ++i)
                #pragma unroll
                for (int j = 0; j < 4; ++j)
                    acc[i][j] = __builtin_amdgcn_mfma_f32_16x16x32_bf16(
                        af[i], bfr[j], acc[i][j], 0, 0, 0);
        }
        __syncthreads();
    }

    // ---- epilogue: per-wave transpose + full-row LN (two-pass, f32) ----
    float* wreg = (float*)smraw + w * 2048;      // 32 rows x 64 cols per wave
    const int gn0 = w * 64 + l15 * 4;
    float4 bias4 = *(const float4*)&bias[gn0];
    float4 g4 = make_float4(0.f, 0.f, 0.f, 0.f), b4 = g4;
    if (Y) { g4 = *(const float4*)&lng[gn0]; b4 = *(const float4*)&lnb[gn0]; }

    #pragma unroll
    for (int ci = 0; ci < 2; ++ci) {
        #pragma unroll
        for (int i2 = 0; i2 < 2; ++i2) {
            int i = ci * 2 + i2;
            #pragma unroll
            for (int j = 0; j < 4; ++j) {
                float* col = &wreg[(i2 * 16 + quad * 4) * 64 + j * 16 + l15];
                #pragma unroll
                for (int r = 0; r < 4; ++r) col[r * 64] = acc[i][j][r];
            }
        }
        // pass A: bias + residual (+PE); store back; row-sum partials
        #pragma unroll
        for (int rr = 0; rr < 8; ++rr) {
            int rl = rr * 4 + quad;
            int gm = m0 + ci * 32 + rl;
            float4 v = *(float4*)&wreg[rl * 64 + l15 * 4];
            v.x += bias4.x; v.y += bias4.y; v.z += bias4.z; v.w += bias4.w;
            size_t crow = (size_t)gm;
            if (rc_mod > 0) crow = (size_t)(gm / rc_mod) * 449 + (gm % rc_mod);
            if (R) {
                float4 r4 = *(const float4*)&R[crow * 256 + gn0];
                v.x += r4.x; v.y += r4.y; v.z += r4.z; v.w += r4.w;
            }
            if (pe_mode) {
                int bi = gm / TFRONT, t = gm - bi * TFRONT;
                float ft = (float)t;
                float f0 = __expf(-9.210340371976184f * (float)gn0 * (1.f / 256.f));
                float f1 = __expf(-9.210340371976184f * (float)(gn0 + 2) * (1.f / 256.f));
                float a0 = ft * f0, a1 = ft * f1;
                v.x += __sinf(a0); v.y += __cosf(a0);
                v.z += __sinf(a1); v.w += __cosf(a1);
            }
            *(float4*)&wreg[rl * 64 + l15 * 4] = v;
            float s = (v.x + v.y) + (v.z + v.w);
            s += __shfl_xor(s, 1); s += __shfl_xor(s, 2);
            s += __shfl_xor(s, 4); s += __shfl_xor(s, 8);
            if (l15 == 0) sums[rl * 4 + w] = s;
        }
        __syncthreads();
        if (tid < 32)
            mst[tid] = (sums[tid * 4] + sums[tid * 4 + 1] +
                        sums[tid * 4 + 2] + sums[tid * 4 + 3]) * (1.f / 256.f);
        __syncthreads();
        // pass B: variance partials
        #pragma unroll
        for (int rr = 0; rr < 8; ++rr) {
            int rl = rr * 4 + quad;
            float4 v = *(float4*)&wreg[rl * 64 + l15 * 4];
            float m = mst[rl];
            float dx = v.x - m, dy = v.y - m, dz = v.z - m, dw = v.w - m;
            float s2 = (dx * dx + dy * dy) + (dz * dz + dw * dw);
            s2 += __shfl_xor(s2, 1); s2 += __shfl_xor(s2, 2);
            s2 += __shfl_xor(s2, 4); s2 += __shfl_xor(s2, 8);
            if (l15 == 0) sqs[rl * 4 + w] = s2;
        }
        __syncthreads();
        if (tid < 32)
            mst[32 + tid] = rsqrtf((sqs[tid * 4] + sqs[tid * 4 + 1] +
                                    sqs[tid * 4 + 2] + sqs[tid * 4 + 3]) * (1.f / 256.f) + 1e-5f);
        __syncthreads();
        // pass C: write C (f32) + Y (bf16 LN)
        #pragma unroll
        for (int rr = 0; rr < 8; ++rr) {
            int rl = rr * 4 + quad;
            int gm = m0 + ci * 32 + rl;
            float4 v = *(float4*)&wreg[rl * 64 + l15 * 4];
            if (pe_mode) {
                int bi = gm / TFRONT, t = gm - bi * TFRONT;
                *(float4*)&C[(size_t)(bi * 449 + 1 + t) * 256 + gn0] = v;
                if (Y && t != TFRONT - 1) {
                    float m = mst[rl], rs = mst[32 + rl];
                    *(uint2*)&Y[(size_t)(gm + 1) * 256 + gn0] = make_uint2(
                        pack2bf((v.x - m) * rs * g4.x + b4.x, (v.y - m) * rs * g4.y + b4.y),
                        pack2bf((v.z - m) * rs * g4.z + b4.z, (v.w - m) * rs * g4.w + b4.w));
                }
            } else {
                size_t crow = (size_t)gm;
                if (rc_mod > 0) crow = (size_t)(gm / rc_mod) * 449 + (gm % rc_mod);
                *(float4*)&C[crow * 256 + gn0] = v;
                if (Y) {
                    float m = mst[rl], rs = mst[32 + rl];
                    *(uint2*)&Y[(size_t)gm * 256 + gn0] = make_uint2(
                        pack2bf((v.x - m) * rs * g4.x + b4.x, (v.y - m) * rs * g4.y + b4.y),
                        pack2bf((v.z - m) * rs * g4.z + b4.z, (v.w - m) * rs * g4.w + b4.w));
                }
            }
        }
        __syncthreads();
    }
}

// ---- prep: transposes + conv repack + BN + guards + cls copy + cls LN ------
__global__ __launch_bounds__(256) void prep_all(
    const float* __restrict__ ipw,  const float* __restrict__ mpw,
    const float* __restrict__ qkvw, const float* __restrict__ outw,
    const float* __restrict__ fw1,  const float* __restrict__ fw2,
    const float* __restrict__ cw1,
    ushort_t* ipwT, ushort_t* mpwT, ushort_t* qkvT, ushort_t* outwT,
    ushort_t* fw1T, ushort_t* fw2T, ushort_t* cw1T,
    const float* __restrict__ convw, ushort_t* wrepT,
    const float* __restrict__ bg, const float* __restrict__ bb,
    const float* __restrict__ rm, const float* __restrict__ rv,
    float* bnsc, float* bnsh,
    ushort_t* h448g, const float* __restrict__ clstok, float* h449,
    const float* __restrict__ ln1g0, const float* __restrict__ ln1b0,
    ushort_t* clsY)
{
    __shared__ float redp[4];
    const int bid = blockIdx.x;
    if (bid >= 3239) {                        // LN(cls_token) w/ layer-0 ln1 -> bufB2 cls rows
        const int d = threadIdx.x;
        float v = clstok[d];
        float s = v;
        #pragma unroll
        for (int o = 32; o > 0; o >>= 1) s += __shfl_down(s, o, 64);
        if ((d & 63) == 0) redp[d >> 6] = s;
        __syncthreads();
        float mean = (redp[0] + redp[1] + redp[2] + redp[3]) * (1.f / 256.f);
        __syncthreads();
        float diff = v - mean;
        float s2 = diff * diff;
        #pragma unroll
        for (int o = 32; o > 0; o >>= 1) s2 += __shfl_down(s2, o, 64);
        if ((d & 63) == 0) redp[d >> 6] = s2;
        __syncthreads();
        float rstd = rsqrtf((redp[0] + redp[1] + redp[2] + redp[3]) * (1.f / 256.f) + 1e-5f);
        ushort_t y = f2bf(diff * rstd * ln1g0[d] + ln1b0[d]);
        for (int b = 0; b < BB; ++b)
            clsY[(size_t)(b * TFRONT) * 256 + d] = y;
        return;
    }
    if (bid >= 3175) {                        // cls-token copy into h449 row 0
        int b = bid - 3175;
        h449[(size_t)b * TTT * 256 + threadIdx.x] = clstok[threadIdx.x];
        return;
    }
    if (bid >= 3111) {                        // zero guard rows of h448g
        int b = bid - 3111;
        #pragma unroll
        for (int j = 0; j < 8; ++j)
            h448g[(size_t)(b * GROWS + j) * 256 + threadIdx.x] = 0;
        return;
    }
    if (bid >= 3108) {                        // BN folding
        int i = (bid - 3108) * 256 + threadIdx.x;
        if (i < 768) {
            float sc = rsqrtf(rv[i] + 1e-5f) * bg[i];
            bnsc[i] = sc;
            bnsh[i] = bb[i] - rm[i] * sc;
        }
        return;
    }
    if (bid >= 804) {                         // conv weight repack
        int i = (bid - 804) * 256 + threadIdx.x;
        int s = i / 196608; int o = i - s * 196608;
        int ci = o & 255; int t3 = (o >> 8) % 3; int co = o / 768;
        wrepT[i] = f2bf(convw[(((size_t)s * 256 + co) * 256 + ci) * 3 + t3]);
        return;
    }
    const float* src; ushort_t* dst; int K, N, local;
    if (bid < 4)        { src = ipw;  dst = ipwT;  K = 64;   N = 256;  local = bid; }
    else if (bid < 20)  { src = mpw;  dst = mpwT;  K = 256;  N = 256;  local = bid - 4; }
    else if (bid < 212) { int l = bid - 20;  int z = l / 48; l -= z * 48;
                          src = qkvw + (size_t)z * 196608; dst = qkvT + (size_t)z * 196608;
                          K = 256;  N = 768;  local = l; }
    else if (bid < 276) { int l = bid - 212; int z = l / 16; l -= z * 16;
                          src = outw + (size_t)z * 65536;  dst = outwT + (size_t)z * 65536;
                          K = 256;  N = 256;  local = l; }
    else if (bid < 532) { int l = bid - 276; int z = l / 64; l -= z * 64;
                          src = fw1 + (size_t)z * 262144;  dst = fw1T + (size_t)z * 262144;
                          K = 256;  N = 1024; local = l; }
    else if (bid < 788) { int l = bid - 532; int z = l / 64; l -= z * 64;
                          src = fw2 + (size_t)z * 262144;  dst = fw2T + (size_t)z * 262144;
                          K = 1024; N = 256;  local = l; }
    else                { src = cw1;  dst = cw1T;  K = 256;  N = 256;  local = bid - 788; }

    __shared__ float tile[64][65];
    int nt = N / 64;
    int n0 = (local % nt) * 64, k0 = (local / nt) * 64;
    int tx = threadIdx.x & 63, ty = threadIdx.x >> 6;
    #pragma unroll
    for (int i = 0; i < 16; ++i)
        tile[i * 4 + ty][tx] = src[(size_t)(k0 + i * 4 + ty) * N + n0 + tx];
    __syncthreads();
    #pragma unroll
    for (int i = 0; i < 16; ++i) {
        int n = i * 4 + ty;
        dst[(size_t)(n0 + n) * K + k0 + tx] = f2bf(tile[tx][n]);
    }
}

// ---------------- gate softmax + fuse, wave-per-row ----------------
__global__ __launch_bounds__(256) void gate_fuse(
    const ushort_t* __restrict__ conv,  // [3][Mrows][256]
    const float* __restrict__ gw, const float* __restrict__ gb,
    ushort_t* __restrict__ fused, int Mrows)
{
    const int w = threadIdx.x >> 6, lane = threadIdx.x & 63;
    const int m = blockIdx.x * 4 + w;
    const int d0 = lane * 4;
    float vals[3][4];
    float p0 = 0.f, p1 = 0.f, p2 = 0.f;
    #pragma unroll
    for (int s = 0; s < 3; ++s) {
        uint2 pk = *(const uint2*)&conv[((size_t)s * Mrows + m) * 256 + d0];
        vals[s][0] = bf2f(pk.x & 0xffff); vals[s][1] = bf2f(pk.x >> 16);
        vals[s][2] = bf2f(pk.y & 0xffff); vals[s][3] = bf2f(pk.y >> 16);
        #pragma unroll
        for (int e = 0; e < 4; ++e) {
            const float* wp = gw + (size_t)(s * 256 + d0 + e) * 3;
            float v = vals[s][e];
            p0 += v * wp[0]; p1 += v * wp[1]; p2 += v * wp[2];
        }
    }
    #pragma unroll
    for (int o = 32; o > 0; o >>= 1) {
        p0 += __shfl_xor(p0, o); p1 += __shfl_xor(p1, o); p2 += __shfl_xor(p2, o);
    }
    float l0 = p0 + gb[0], l1 = p1 + gb[1], l2 = p2 + gb[2];
    float mx = fmaxf(l0, fmaxf(l1, l2));
    float e0 = __expf(l0 - mx), e1 = __expf(l1 - mx), e2 = __expf(l2 - mx);
    float inv = 1.f / (e0 + e1 + e2);
    float g0 = e0 * inv, g1 = e1 * inv, g2 = e2 * inv;
    unsigned r0 = pack2bf(vals[0][0] * g0 + vals[1][0] * g1 + vals[2][0] * g2,
                          vals[0][1] * g0 + vals[1][1] * g1 + vals[2][1] * g2);
    unsigned r1 = pack2bf(vals[0][2] * g0 + vals[1][2] * g1 + vals[2][2] * g2,
                          vals[0][3] * g0 + vals[1][3] * g1 + vals[2][3] * g2);
    *(uint2*)&fused[(size_t)m * 256 + d0] = make_uint2(r0, r1);
}

// ---------------- attention v8b: compact strides, window [qb-32, qb+47] ------
#define KP    480
#define KPAD  36
#define VPAD  488
#define PTPAD 40
__global__ __launch_bounds__(256, 2) void attn8_kernel(
    const ushort_t* __restrict__ qkv,
    const float* __restrict__ alpha,
    ushort_t* __restrict__ O,
    int kst, int nqt, int ost)
{
    __shared__ ushort_t sK[KP][KPAD];
    __shared__ ushort_t sVt[32][VPAD];
    __shared__ ushort_t sPT[4][16][PTPAD];
    __shared__ float sRed[4];

    const int bh = blockIdx.x;
    const int b = bh >> 3, h = bh & 7;
    const int tid = threadIdx.x;
    const int w = tid >> 6, lane = tid & 63;
    const int l15 = lane & 15, quad = lane >> 4;
    const float LOG2E = 1.4426950408889634f;
    const float scale2 = 0.17677669529663687f * LOG2E;

    float av = alpha[h];
    float a_sp = (av > 20.f) ? av : log1pf(__expf(av));
    const float a_h = a_sp * LOG2E;

    {
        int r0 = tid >> 2, c = (tid & 3) * 8;
        float knmax = 0.f;
        for (int r = r0; r < kst; r += 64) {
            const ushort_t* src = qkv + ((size_t)(b * kst + r)) * 768 + 256 + h * 32 + c;
            short8 kv = *(const short8*)src;
            short8 vv = *(const short8*)(src + 256);
            *(short8*)&sK[r][c] = kv;
            float ssq = 0.f;
            #pragma unroll
            for (int j = 0; j < 8; ++j) {
                float kf = bf2f(((const ushort_t*)&kv)[j]);
                ssq += kf * kf;
                sVt[c + j][r] = ((const ushort_t*)&vv)[j];
            }
            ssq += __shfl_xor(ssq, 1);
            ssq += __shfl_xor(ssq, 2);
            knmax = fmaxf(knmax, ssq);
        }
        #pragma unroll
        for (int o = 32; o > 0; o >>= 1) knmax = fmaxf(knmax, __shfl_xor(knmax, o));
        if (lane == 0) sRed[w] = knmax;
    }
    __syncthreads();
    const float kmax2 = fmaxf(fmaxf(sRed[0], sRed[1]), fmaxf(sRed[2], sRed[3]));

    for (int qt = w; qt < nqt; qt += 4) {
        const int qb = qt * 16;
        const int qrow = qb + l15;
        short8 qfrag = *(const short8*)(qkv + ((size_t)(b * kst + qrow)) * 768 + h * 32 + quad * 8);
        const f32x4 z = {0.f, 0.f, 0.f, 0.f};

        float qn = 0.f;
        #pragma unroll
        for (int j = 0; j < 8; ++j) { float f = bf2f(qfrag[j]); qn += f * f; }
        qn += __shfl_xor(qn, 16);
        qn += __shfl_xor(qn, 32);
        const float Mr = scale2 * sqrtf(qn * kmax2);
        const float fq = (float)qrow;

        int ch_lo = (qb - 32) >> 5; if (ch_lo < 0) ch_lo = 0;
        int ch_hi = (qb + 47) >> 5;
        const int ch_max = (kst >> 5) - 1;
        if (ch_hi > ch_max) ch_hi = ch_max;

        f32x4 o0 = z, o1 = z;
        float lsum = 0.f;
        for (int ch = ch_lo; ch <= ch_hi; ++ch) {
            const int kb = ch * 32;
            short8 kf0 = *(const short8*)&sK[kb + l15][quad * 8];
            short8 kf1 = *(const short8*)&sK[kb + 16 + l15][quad * 8];
            f32x4 s0 = __builtin_amdgcn_mfma_f32_16x16x32_bf16(kf0, qfrag, z, 0, 0, 0);
            f32x4 s1 = __builtin_amdgcn_mfma_f32_16x16x32_bf16(kf1, qfrag, z, 0, 0, 0);
            float p0[4], p1[4];
            #pragma unroll
            for (int r = 0; r < 4; ++r) {
                int k0 = kb + quad * 4 + r;
                int k1 = k0 + 16;
                float b0 = s0[r] * scale2 - (a_h * fabsf(fq - (float)k0) + Mr);
                float b1 = s1[r] * scale2 - (a_h * fabsf(fq - (float)k1) + Mr);
                p0[r] = exp2f(b0);
                p1[r] = exp2f(b1);
            }
            lsum += (p0[0] + p0[1]) + (p0[2] + p0[3]) + (p1[0] + p1[1]) + (p1[2] + p1[3]);
            unsigned* prow = (unsigned*)&sPT[w][l15][0];
            prow[quad * 2]     = pack2bf(p0[0], p0[1]);
            prow[quad * 2 + 1] = pack2bf(p0[2], p0[3]);
            prow[8 + quad * 2]     = pack2bf(p1[0], p1[1]);
            prow[8 + quad * 2 + 1] = pack2bf(p1[2], p1[3]);
            short8 pB = *(const short8*)&sPT[w][l15][quad * 8];
            short8 v0 = *(const short8*)&sVt[l15][kb + quad * 8];
            short8 v1 = *(const short8*)&sVt[16 + l15][kb + quad * 8];
            o0 = __builtin_amdgcn_mfma_f32_16x16x32_bf16(v0, pB, o0, 0, 0, 0);
            o1 = __builtin_amdgcn_mfma_f32_16x16x32_bf16(v1, pB, o1, 0, 0, 0);
        }
        lsum += __shfl_xor(lsum, 16);
        lsum += __shfl_xor(lsum, 32);

        {
            float inv = 1.f / lsum;
            unsigned* dst = (unsigned*)&O[((size_t)(b * ost + qrow)) * 256 + h * 32 + quad * 4];
            dst[0] = pack2bf(o0[0] * inv, o0[1] * inv);
            dst[1] = pack2bf(o0[2] * inv, o0[3] * inv);
            dst[8] = pack2bf(o1[0] * inv, o1[1] * inv);
            dst[9] = pack2bf(o1[2] * inv, o1[3] * inv);
        }
    }
}

// ---------------- fused head: final LN + cls MLP + logit (1 block/batch) -----
__global__ __launch_bounds__(256) void head_kernel(
    const float* __restrict__ h449,
    const float* __restrict__ fing, const float* __restrict__ finb,
    const ushort_t* __restrict__ cw1T, const float* __restrict__ cb1,
    const float* __restrict__ cw2, const float* __restrict__ b2,
    float* __restrict__ out)
{
    __shared__ float xn[256];
    __shared__ float red[4];
    const int b = blockIdx.x, d = threadIdx.x;
    float v = h449[(size_t)b * TTT * 256 + d];
    float s = v;
    #pragma unroll
    for (int o = 32; o > 0; o >>= 1) s += __shfl_down(s, o, 64);
    if ((d & 63) == 0) red[d >> 6] = s;
    __syncthreads();
    float mean = (red[0] + red[1] + red[2] + red[3]) * (1.f / 256.f);
    __syncthreads();
    float diff = v - mean;
    float s2 = diff * diff;
    #pragma unroll
    for (int o = 32; o > 0; o >>= 1) s2 += __shfl_down(s2, o, 64);
    if ((d & 63) == 0) red[d >> 6] = s2;
    __syncthreads();
    float rstd = rsqrtf((red[0] + red[1] + red[2] + red[3]) * (1.f / 256.f) + 1e-5f);
    xn[d] = diff * rstd * fing[d] + finb[d];
    __syncthreads();
    const ushort_t* wrow = cw1T + (size_t)d * 256;
    float acc = 0.f;
    #pragma unroll 4
    for (int k = 0; k < 256; k += 8) {
        short8 wv = *(const short8*)&wrow[k];
        #pragma unroll
        for (int j = 0; j < 8; ++j) acc += xn[k + j] * bf2f(((const ushort_t*)&wv)[j]);
    }
    float p = gelu_f(acc + cb1[d]) * cw2[d];
    #pragma unroll
    for (int o = 32; o > 0; o >>= 1) p += __shfl_down(p, o, 64);
    __syncthreads();
    if ((d & 63) == 0) red[d >> 6] = p;
    __syncthreads();
    if (d == 0) out[b] = red[0] + red[1] + red[2] + red[3] + b2[0];
}

// ---------------- orchestration ----------------
extern "C" void kernel_launch(void* const* d_in, const int* in_sizes, int n_in,
                              void* d_out, int out_size, void* d_ws, size_t ws_size,
                              hipStream_t stream)
{
    const float* x      = (const float*)d_in[0];
    const float* ipw    = (const float*)d_in[1];
    const float* ipb    = (const float*)d_in[2];
    const float* convw  = (const float*)d_in[3];
    const float* convb  = (const float*)d_in[4];
    const float* bng    = (const float*)d_in[5];
    const float* bnb    = (const float*)d_in[6];
    const float* bnrm   = (const float*)d_in[7];
    const float* bnrv   = (const float*)d_in[8];
    const float* gatew  = (const float*)d_in[9];
    const float* gateb  = (const float*)d_in[10];
    const float* mpw    = (const float*)d_in[11];
    const float* mpb    = (const float*)d_in[12];
    const float* clstok = (const float*)d_in[13];
    const float* qkvw   = (const float*)d_in[14];
    const float* qkvb   = (const float*)d_in[15];
    const float* outw   = (const float*)d_in[16];
    const float* outb   = (const float*)d_in[17];
    const float* alpha  = (const float*)d_in[18];
    const float* ln1g   = (const float*)d_in[19];
    const float* ln1b   = (const float*)d_in[20];
    const float* ln2g   = (const float*)d_in[21];
    const float* ln2b   = (const float*)d_in[22];
    const float* fw1    = (const float*)d_in[23];
    const float* fb1    = (const float*)d_in[24];
    const float* fw2    = (const float*)d_in[25];
    const float* fb2    = (const float*)d_in[26];
    const float* fing   = (const float*)d_in[27];
    const float* finb   = (const float*)d_in[28];
    const float* cw1    = (const float*)d_in[29];
    const float* cb1    = (const float*)d_in[30];
    const float* cw2    = (const float*)d_in[31];
    const float* cb2    = (const float*)d_in[32];

    const int KL[4] = {160, 128, 96, 64};
    const int QL[4] = {128, 96, 64, 16};

    // ---- workspace layout ----
    char* base = (char*)d_ws;
    size_t off = 0;
    auto alloc = [&](size_t bytes) { char* p = base + off; off += (bytes + 255) & ~(size_t)255; return p; };
    float*    h448  = (float*)alloc((size_t)MFRONT * 256 * 4);
    float*    h449  = (float*)alloc((size_t)MPAD * 256 * 4);
    float*    bufA  = (float*)alloc((size_t)MFRONT * 768 * 4);
    ushort_t* conv_bf = (ushort_t*)bufA;
    ushort_t* qkv_bf  = (ushort_t*)bufA;
    ushort_t* bufMid  = (ushort_t*)bufA;
    ushort_t* bufB  = (ushort_t*)alloc((size_t)MFRONT * 256 * 2);
    ushort_t* bufB2 = (ushort_t*)alloc((size_t)MFRONT * 256 * 2);
    ushort_t* bufC  = (ushort_t*)alloc((size_t)64 * 128 * 256 * 2);
    ushort_t* h448g = (ushort_t*)alloc((size_t)BB * GROWS * 256 * 2);
    ushort_t* wrepT = (ushort_t*)alloc((size_t)3 * 256 * 768 * 2);
    ushort_t* ipwT  = (ushort_t*)alloc((size_t)64 * 256 * 2);
    ushort_t* mpwT  = (ushort_t*)alloc((size_t)256 * 256 * 2);
    ushort_t* qkvT  = (ushort_t*)alloc((size_t)4 * 768 * 256 * 2);
    ushort_t* outwT = (ushort_t*)alloc((size_t)4 * 256 * 256 * 2);
    ushort_t* fw1T  = (ushort_t*)alloc((size_t)4 * 1024 * 256 * 2);
    ushort_t* fw2T  = (ushort_t*)alloc((size_t)4 * 256 * 1024 * 2);
    ushort_t* cw1T  = (ushort_t*)alloc((size_t)256 * 256 * 2);
    float*    bnsc  = (float*)alloc(768 * 4);
    float*    bnsh  = (float*)alloc(768 * 4);

    auto gemm = [&](const ushort_t* A, const ushort_t* Bt, void* C, ushort_t* C2,
                    const float* bias, const float* scl, const float* shf, const float* R,
                    int M, int N, int K, int a_dil, int gelu_fl, int omode, int pemode,
                    int rc_mod = 0, int gz = 1) {
        dim3 grid(N / 128, M / 128, gz);
        hipLaunchKernelGGL(gemm_bf16, grid, dim3(256), 0, stream,
                           A, Bt, C, C2, bias, scl, shf, R, M, N, K, a_dil, gelu_fl,
                           omode, pemode, rc_mod);
    };
    auto gemmln = [&](const ushort_t* A, const ushort_t* Bt, float* C, ushort_t* Yp,
                      const float* bias, const float* R,
                      const float* g, const float* b,
                      int M, int K, int pemode, int rcm) {
        hipLaunchKernelGGL(gemm_ln, dim3(1, M / 64), dim3(256), 0, stream,
                           A, Bt, C, Yp, bias, R, g, b, M, K, pemode, rcm);
    };

    // ---- prep: transposes + conv repack + BN + guard zero + cls copy/LN ----
    hipLaunchKernelGGL(prep_all, dim3(3240), dim3(256), 0, stream,
                       ipw, mpw, qkvw, outw, fw1, fw2, cw1,
                       ipwT, mpwT, qkvT, outwT, fw1T, fw2T, cw1T,
                       convw, wrepT, bng, bnb, bnrm, bnrv, bnsc, bnsh,
                       h448g, clstok, h449, ln1g, ln1b, bufB2);

    // ---- input projection on rows t<160: h448 f32 + h448g bf16 (guarded) ----
    gemm((const ushort_t*)x, ipwT, h448, h448g, ipb, nullptr, nullptr, nullptr,
         MFRONT, 256, 64, -2, 0, 2, 0);

    // ---- conv (3 scales in z), DMA staging from h448g, fused gelu+BN ----
    gemm(h448g, wrepT, conv_bf, nullptr, convb, bnsc, bnsh, nullptr,
         MFRONT, 256, 768, -1, 1, 1, 0, 0, 3);
    hipLaunchKernelGGL(gate_fuse, dim3(MFRONT / 4), dim3(256), 0, stream,
                       conv_bf, gatew, gateb, bufB, MFRONT);
    // ms_proj + residual + PE -> h449 rows 1..160; fused LN1(l0) -> bufB2
    gemmln(bufB, mpwT, h449, bufB2, mpb, h448, ln1g, ln1b,
           MFRONT, 256, 1, 0);

    // ---- transformer layers on the shrinking cone ----
    for (int l = 0; l < LAYERS; ++l) {
        const int Kl = KL[l], Ql = QL[l];
        const int MK = 64 * Kl, MQ = 64 * Ql;
        gemm(bufB2, qkvT + (size_t)l * 768 * 256, qkv_bf, nullptr, qkvb + l * 768,
             nullptr, nullptr, nullptr, MK, 768, 256, 0, 0, 1, 0);
        hipLaunchKernelGGL(attn8_kernel, dim3(BB * HEADS), dim3(256), 0, stream,
                           qkv_bf, alpha + l * HEADS, bufC, Kl, Ql / 16, Ql);
        // out-proj + residual -> h449 ; fused LN2(l) -> bufB2
        gemmln(bufC, outwT + (size_t)l * 65536, h449, bufB2, outb + l * 256,
               h449, ln2g + l * 256, ln2b + l * 256, MQ, 256, 0, Ql);
        gemm(bufB2, fw1T + (size_t)l * 262144, bufMid, nullptr, fb1 + l * 1024,
             nullptr, nullptr, nullptr, MQ, 1024, 256, 0, 1, 1, 0);
        // ffn2 + residual -> h449 ; fused LN1(l+1) -> bufB2 (skip on last layer)
        gemmln(bufMid, fw2T + (size_t)l * 262144, h449,
               (l < 3) ? bufB2 : nullptr, fb2 + l * 256, h449,
               (l < 3) ? ln1g + (l + 1) * 256 : nullptr,
               (l < 3) ? ln1b + (l + 1) * 256 : nullptr,
               MQ, 1024, 0, Ql);
    }

    // ---- fused head: final LN + cls MLP + logit ----
    hipLaunchKernelGGL(head_kernel, dim3(BB), dim3(256), 0, stream,
                       h449, fing, finb, cw1T, cb1, cw2, cb2, (float*)d_out);
}

// Round 3
// 538.362 us; speedup vs baseline: 1.0842x; 1.0842x over previous
//
#include <hip/hip_runtime.h>
#include <hip/hip_bf16.h>
#include <math.h>

// ---------------- model constants ----------------
#define BB   64
#define TT   448
#define TTT  449
#define DIM  256
#define HEADS 8
#define HD   32
#define LAYERS 4
#define FFD  1024
#define INDIM 64
#define MPAD 28800
// dependency cone (window [qb-32, qb+47], chunk-granular):
#define TFRONT 160            // front-end rows/batch
#define MFRONT (BB*TFRONT)    // 10240
#define GROWS  168            // guarded rows/batch in h448g (8 zero + 160)

typedef __attribute__((ext_vector_type(8))) short short8;
typedef __attribute__((ext_vector_type(4))) float f32x4;
typedef unsigned short ushort_t;

__device__ __forceinline__ float gelu_f(float x) {
    float x2 = x * x;
    float m = 0.10295219f * x2 + 2.3022635f;
    float t = exp2f(-x * m);
    return x * (1.f / (1.f + t));
}
__device__ __forceinline__ ushort_t f2bf(float x) {
    unsigned u; __builtin_memcpy(&u, &x, 4);
    return (ushort_t)((u + 0x8000u) >> 16);
}
__device__ __forceinline__ unsigned pack2bf(float a, float b) {
    unsigned ua, ub;
    __builtin_memcpy(&ua, &a, 4); __builtin_memcpy(&ub, &b, 4);
    return ((ua + 0x8000u) >> 16) | ((ub + 0x8000u) & 0xffff0000u);
}
__device__ __forceinline__ float bf2f(ushort_t u) {
    unsigned v = ((unsigned)u) << 16; float f; __builtin_memcpy(&f, &v, 4); return f;
}
__device__ __forceinline__ void gload16(const ushort_t* g, ushort_t* l) {
    __builtin_amdgcn_global_load_lds(
        (const __attribute__((address_space(1))) void*)g,
        (__attribute__((address_space(3))) void*)l, 16, 0, 0);
}

// ---------------- bf16 MFMA GEMM v7 (R12 structure) ----------------
// C[m,n] = sum_k A[m,k] * Bt[n,k]
// a_dil > 0 : conv mode — A is guard-padded h448g [b*168 + 8 + t], t=gm%160.
// a_dil == -1: merged conv (blockIdx.z selects scale s: a_dil=1<<s).
// a_dil == -2: A is f32 x [b*448 + t] (t=gm%160); C2 written to h448g layout.
// rc_mod > 0: R and C row = (gm/rc_mod)*449 + gm%rc_mod (h449 layout).
// pe_mode: C row = (gm/160)*449 + 1 + gm%160, add sinusoidal PE (f32 out).
__global__ __launch_bounds__(256, 3) void gemm_bf16(
    const ushort_t* __restrict__ A, const ushort_t* __restrict__ Bt,
    void* __restrict__ C, ushort_t* __restrict__ C2,
    const float* __restrict__ bias,
    const float* __restrict__ scalev, const float* __restrict__ shiftv,
    const float* __restrict__ R,
    int M, int N, int K, int a_dil, int do_gelu, int out_mode, int pe_mode,
    int rc_mod)
{
    __shared__ ushort_t smem[2 * 128 * 64];
    ushort_t* As = smem;
    ushort_t* Bs = smem + 128 * 64;
    const int tid = threadIdx.x;
    const int lane = tid & 63, w = tid >> 6;
    const int wm = w >> 1, wn = w & 1;
    const int l15 = lane & 15, quad = lane >> 4;
    const int m0 = blockIdx.y * 128, n0 = blockIdx.x * 128;
    const int sr = lane >> 3, ss = lane & 7;
    const int gsw = ss ^ sr;

    if (a_dil == -1) {                 // merged conv dispatch
        int z = blockIdx.z;
        a_dil = 1 << z;
        Bt += (size_t)z * 196608;
        C = (void*)((ushort_t*)C + (size_t)z * MFRONT * 256);
        bias += z * 256; scalev += z * 256; shiftv += z * 256;
    }
    const ushort_t* aconv[4];
    if (a_dil > 0) {
        #pragma unroll
        for (int j = 0; j < 4; ++j) {
            int r = (w * 4 + j) * 8 + sr;
            int gm = m0 + r;
            int b = gm / TFRONT, t = gm - b * TFRONT;
            aconv[j] = A + ((size_t)(b * GROWS + 8 + t)) * 256 + gsw * 8;
        }
    }
    f32x4 acc[4][4] = {};

    for (int k0 = 0; k0 < K; k0 += 64) {
        if (a_dil > 0) {
            int tap = k0 >> 8;
            int aoff = (k0 & 255) - ((2 - tap) * a_dil) * 256;
            #pragma unroll
            for (int j = 0; j < 4; ++j)
                gload16(aconv[j] + aoff, &As[(w * 4 + j) * 512]);
        } else if (a_dil == -2) {
            const float* Af = (const float*)A;
            #pragma unroll
            for (int j = 0; j < 4; ++j) {
                int r = (w * 4 + j) * 8 + sr;
                int gm = m0 + r;
                int b = gm / TFRONT, t = gm - b * TFRONT;
                const float* ap = Af + ((size_t)b * 448 + t) * K + k0 + gsw * 8;
                float4 a0 = *(const float4*)ap;
                float4 a1 = *(const float4*)(ap + 4);
                uint2 lo = make_uint2(pack2bf(a0.x, a0.y), pack2bf(a0.z, a0.w));
                uint2 hi = make_uint2(pack2bf(a1.x, a1.y), pack2bf(a1.z, a1.w));
                *(uint2*)&As[r * 64 + ss * 8] = lo;
                *(uint2*)&As[r * 64 + ss * 8 + 4] = hi;
            }
        } else {
            #pragma unroll
            for (int j = 0; j < 4; ++j) {
                int r = (w * 4 + j) * 8 + sr;
                int g = ss ^ (r & 7);
                gload16(&A[(size_t)(m0 + r) * K + k0 + g * 8], &As[(w * 4 + j) * 512]);
            }
        }
        #pragma unroll
        for (int j = 0; j < 4; ++j) {
            int r = (w * 4 + j) * 8 + sr;
            int g = ss ^ (r & 7);
            gload16(&Bt[(size_t)(n0 + r) * K + k0 + g * 8], &Bs[(w * 4 + j) * 512]);
        }
        __syncthreads();
        #pragma unroll
        for (int ks = 0; ks < 2; ++ks) {
            short8 af[4], bfr[4];
            #pragma unroll
            for (int i = 0; i < 4; ++i) {
                int row = wm * 64 + i * 16 + l15;
                af[i] = *(const short8*)&As[row * 64 + (((ks * 4 + quad) ^ (l15 & 7)) * 8)];
            }
            #pragma unroll
            for (int j = 0; j < 4; ++j) {
                int row = wn * 64 + j * 16 + l15;
                bfr[j] = *(const short8*)&Bs[row * 64 + (((ks * 4 + quad) ^ (l15 & 7)) * 8)];
            }
            #pragma unroll
            for (int i = 0; i < 4; ++i)
                #pragma unroll
                for (int j = 0; j < 4; ++j)
                    acc[i][j] = __builtin_amdgcn_mfma_f32_16x16x32_bf16(
                        af[i], bfr[j], acc[i][j], 0, 0, 0);
        }
        __syncthreads();
    }

    // ---- vectorized epilogue via per-wave LDS transpose ----
    float* wreg = (float*)smem + w * 2048;
    const int gn0 = n0 + wn * 64 + l15 * 4;
    float4 bias4 = bias ? *(const float4*)&bias[gn0] : make_float4(0.f, 0.f, 0.f, 0.f);
    float4 scl4, shf4;
    if (scalev) { scl4 = *(const float4*)&scalev[gn0]; shf4 = *(const float4*)&shiftv[gn0]; }
    else        { scl4 = make_float4(1.f, 1.f, 1.f, 1.f); shf4 = make_float4(0.f, 0.f, 0.f, 0.f); }

    #pragma unroll
    for (int ci = 0; ci < 2; ++ci) {
        #pragma unroll
        for (int i2 = 0; i2 < 2; ++i2) {
            int i = ci * 2 + i2;
            #pragma unroll
            for (int j = 0; j < 4; ++j) {
                float* col = &wreg[(i2 * 16 + quad * 4) * 64 + j * 16 + l15];
                #pragma unroll
                for (int r = 0; r < 4; ++r) col[r * 64] = acc[i][j][r];
            }
        }
        #pragma unroll
        for (int rr = 0; rr < 8; ++rr) {
            int rl = rr * 4 + quad;
            float4 v = *(float4*)&wreg[rl * 64 + l15 * 4];
            int gm = m0 + wm * 64 + ci * 32 + rl;
            v.x += bias4.x; v.y += bias4.y; v.z += bias4.z; v.w += bias4.w;
            if (do_gelu) { v.x = gelu_f(v.x); v.y = gelu_f(v.y); v.z = gelu_f(v.z); v.w = gelu_f(v.w); }
            v.x = v.x * scl4.x + shf4.x; v.y = v.y * scl4.y + shf4.y;
            v.z = v.z * scl4.z + shf4.z; v.w = v.w * scl4.w + shf4.w;
            size_t crow = (size_t)gm;
            if (rc_mod > 0) crow = (size_t)(gm / rc_mod) * 449 + (gm % rc_mod);
            if (R) {
                float4 r4 = *(const float4*)&R[crow * N + gn0];
                v.x += r4.x; v.y += r4.y; v.z += r4.z; v.w += r4.w;
            }
            if (pe_mode) {
                int bi = gm / TFRONT, t = gm - bi * TFRONT;
                float ft = (float)t;
                float f0 = __expf(-9.210340371976184f * (float)gn0 * (1.f / 256.f));
                float f1 = __expf(-9.210340371976184f * (float)(gn0 + 2) * (1.f / 256.f));
                float a0 = ft * f0, a1 = ft * f1;
                v.x += __sinf(a0); v.y += __cosf(a0);
                v.z += __sinf(a1); v.w += __cosf(a1);
                *(float4*)&((float*)C)[(size_t)(bi * 449 + 1 + t) * 256 + gn0] = v;
            } else if (out_mode == 1) {
                uint2 pk = make_uint2(pack2bf(v.x, v.y), pack2bf(v.z, v.w));
                *(uint2*)&((ushort_t*)C)[crow * N + gn0] = pk;
            } else {
                *(float4*)&((float*)C)[crow * N + gn0] = v;
                if (out_mode == 2) {
                    int bi = gm / TFRONT, t = gm - bi * TFRONT;
                    size_t grow = (size_t)(bi * GROWS + 8 + t);
                    uint2 pk = make_uint2(pack2bf(v.x, v.y), pack2bf(v.z, v.w));
                    *(uint2*)&C2[grow * N + gn0] = pk;
                }
            }
        }
    }
}

// ---------------- bf16 MFMA GEMM + fused LayerNorm (N=256 full-row tile) ----
// Tile 64x256, 4 waves (each 64 rows x 64-col slice). Epilogue v2:
// - residual loads hoisted (one latency exposure per ci)
// - v held in registers across the stats phase (no LDS re-read passes)
// - one-pass mean/var (E[x^2] - m^2)
// - dedicated shared scratch (no aliasing with the wreg transpose buffer)
// - 2 barriers per ci (4 total)
// pe_mode: C row = b*449+1+t, Y row = gm+1 (skip t==159).
// Y==null: skip LN output (ffn2 of last layer).
__global__ __launch_bounds__(256, 3) void gemm_ln(
    const ushort_t* __restrict__ A, const ushort_t* __restrict__ Bt,
    float* __restrict__ C, ushort_t* __restrict__ Y,
    const float* __restrict__ bias, const float* __restrict__ R,
    const float* __restrict__ lng, const float* __restrict__ lnb,
    int M, int K, int pe_mode, int rc_mod)
{
    __shared__ __align__(16) char smraw[40960];  // As 8KB + Bs 32KB (k-loop); wreg 32KB (epilogue)
    __shared__ float sred[2][32][4];             // [sum|sq][row][wave]
    __shared__ float smean[32];
    __shared__ float srstd[32];
    ushort_t* As = (ushort_t*)smraw;             // 64x64 bf16   (8 KB)
    ushort_t* Bs = (ushort_t*)(smraw + 8192);    // 256x64 bf16  (32 KB)
    const int tid = threadIdx.x;
    const int lane = tid & 63, w = tid >> 6;
    const int l15 = lane & 15, quad = lane >> 4;
    const int m0 = blockIdx.y * 64;
    const int sr = lane >> 3, ss = lane & 7;
    const int gsw = ss ^ sr;

    f32x4 acc[4][4] = {};

    for (int k0 = 0; k0 < K; k0 += 64) {
        #pragma unroll
        for (int j = 0; j < 2; ++j) {            // A: 64 rows = 8 chunks
            int ch = w * 2 + j;
            gload16(&A[(size_t)(m0 + ch * 8 + sr) * K + k0 + gsw * 8], &As[ch * 512]);
        }
        #pragma unroll
        for (int j = 0; j < 8; ++j) {            // B: 256 rows = 32 chunks
            int ch = w * 8 + j;
            gload16(&Bt[(size_t)(ch * 8 + sr) * K + k0 + gsw * 8], &Bs[ch * 512]);
        }
        __syncthreads();
        #pragma unroll
        for (int ks = 0; ks < 2; ++ks) {
            short8 af[4], bfr[4];
            #pragma unroll
            for (int i = 0; i < 4; ++i) {
                int row = i * 16 + l15;
                af[i] = *(const short8*)&As[row * 64 + (((ks * 4 + quad) ^ (l15 & 7)) * 8)];
            }
            #pragma unroll
            for (int j = 0; j < 4; ++j) {
                int row = w * 64 + j * 16 + l15;
                bfr[j] = *(const short8*)&Bs[row * 64 + (((ks * 4 + quad) ^ (l15 & 7)) * 8)];
            }
            #pragma unroll
            for (int i = 0; i < 4; ++i)
                #pragma unroll
                for (int j = 0; j < 4; ++j)
                    acc[i][j] = __builtin_amdgcn_mfma_f32_16x16x32_bf16(
                        af[i], bfr[j], acc[i][j], 0, 0, 0);
        }
        __syncthreads();
    }

    // ---- epilogue v2 ----
    float* wreg = (float*)smraw + w * 2048;      // 32 rows x 64 cols per wave
    const int gn0 = w * 64 + l15 * 4;
    float4 bias4 = *(const float4*)&bias[gn0];
    float4 g4 = make_float4(0.f, 0.f, 0.f, 0.f), b4 = g4;
    if (Y) { g4 = *(const float4*)&lng[gn0]; b4 = *(const float4*)&lnb[gn0]; }
    // PE per-thread frequency constants (column-only dependence), hoisted:
    float pf0 = 0.f, pf1 = 0.f;
    if (pe_mode) {
        pf0 = __expf(-9.210340371976184f * (float)gn0 * (1.f / 256.f));
        pf1 = __expf(-9.210340371976184f * (float)(gn0 + 2) * (1.f / 256.f));
    }

    #pragma unroll
    for (int ci = 0; ci < 2; ++ci) {
        // (a) per-wave transpose acc -> wreg (same-wave RAW, ordered by lgkmcnt)
        #pragma unroll
        for (int i2 = 0; i2 < 2; ++i2) {
            int i = ci * 2 + i2;
            #pragma unroll
            for (int j = 0; j < 4; ++j) {
                float* col = &wreg[(i2 * 16 + quad * 4) * 64 + j * 16 + l15];
                #pragma unroll
                for (int r = 0; r < 4; ++r) col[r * 64] = acc[i][j][r];
            }
        }
        // (b) hoisted residual loads: all 8 issued together, one latency exposure
        float4 rv[8];
        if (R) {
            #pragma unroll
            for (int rr = 0; rr < 8; ++rr) {
                int gm = m0 + ci * 32 + rr * 4 + quad;
                size_t crow = (size_t)gm;
                if (rc_mod > 0) crow = (size_t)(gm / rc_mod) * 449 + (gm % rc_mod);
                rv[rr] = *(const float4*)&R[crow * 256 + gn0];
            }
        }
        // (c) v = acc^T + bias (+R) (+PE), kept in registers; partial sums -> sred
        float4 v[8];
        #pragma unroll
        for (int rr = 0; rr < 8; ++rr) {
            int rl = rr * 4 + quad;
            float4 t4 = *(float4*)&wreg[rl * 64 + l15 * 4];
            t4.x += bias4.x; t4.y += bias4.y; t4.z += bias4.z; t4.w += bias4.w;
            if (R) { t4.x += rv[rr].x; t4.y += rv[rr].y; t4.z += rv[rr].z; t4.w += rv[rr].w; }
            if (pe_mode) {
                int gm = m0 + ci * 32 + rl;
                float ft = (float)(gm - (gm / TFRONT) * TFRONT);
                float a0 = ft * pf0, a1 = ft * pf1;
                t4.x += __sinf(a0); t4.y += __cosf(a0);
                t4.z += __sinf(a1); t4.w += __cosf(a1);
            }
            v[rr] = t4;
            float s  = (t4.x + t4.y) + (t4.z + t4.w);
            float s2 = (t4.x * t4.x + t4.y * t4.y) + (t4.z * t4.z + t4.w * t4.w);
            s  += __shfl_xor(s, 1);  s  += __shfl_xor(s, 2);
            s  += __shfl_xor(s, 4);  s  += __shfl_xor(s, 8);
            s2 += __shfl_xor(s2, 1); s2 += __shfl_xor(s2, 2);
            s2 += __shfl_xor(s2, 4); s2 += __shfl_xor(s2, 8);
            if (l15 == 0) { sred[0][rl][w] = s; sred[1][rl][w] = s2; }
        }
        __syncthreads();
        // (d) cross-wave reduce: mean + rstd in one shot
        if (tid < 32) {
            float sm = (sred[0][tid][0] + sred[0][tid][1]) +
                       (sred[0][tid][2] + sred[0][tid][3]);
            float sq = (sred[1][tid][0] + sred[1][tid][1]) +
                       (sred[1][tid][2] + sred[1][tid][3]);
            float m = sm * (1.f / 256.f);
            smean[tid] = m;
            srstd[tid] = rsqrtf(sq * (1.f / 256.f) - m * m + 1e-5f);
        }
        __syncthreads();
        // (e) write C (f32) + Y (bf16 LN) straight from registers
        #pragma unroll
        for (int rr = 0; rr < 8; ++rr) {
            int rl = rr * 4 + quad;
            int gm = m0 + ci * 32 + rl;
            float vx = v[rr].x, vy = v[rr].y, vz = v[rr].z, vw = v[rr].w;
            if (pe_mode) {
                int bi = gm / TFRONT, t = gm - bi * TFRONT;
                *(float4*)&C[(size_t)(bi * 449 + 1 + t) * 256 + gn0] =
                    make_float4(vx, vy, vz, vw);
                if (Y && t != TFRONT - 1) {
                    float m = smean[rl], rs = srstd[rl];
                    *(uint2*)&Y[(size_t)(gm + 1) * 256 + gn0] = make_uint2(
                        pack2bf((vx - m) * rs * g4.x + b4.x, (vy - m) * rs * g4.y + b4.y),
                        pack2bf((vz - m) * rs * g4.z + b4.z, (vw - m) * rs * g4.w + b4.w));
                }
            } else {
                size_t crow = (size_t)gm;
                if (rc_mod > 0) crow = (size_t)(gm / rc_mod) * 449 + (gm % rc_mod);
                *(float4*)&C[crow * 256 + gn0] = make_float4(vx, vy, vz, vw);
                if (Y) {
                    float m = smean[rl], rs = srstd[rl];
                    *(uint2*)&Y[(size_t)gm * 256 + gn0] = make_uint2(
                        pack2bf((vx - m) * rs * g4.x + b4.x, (vy - m) * rs * g4.y + b4.y),
                        pack2bf((vz - m) * rs * g4.z + b4.z, (vw - m) * rs * g4.w + b4.w));
                }
            }
        }
    }
}

// ---- prep: transposes + conv repack + BN + guards + cls copy + cls LN ------
__global__ __launch_bounds__(256) void prep_all(
    const float* __restrict__ ipw,  const float* __restrict__ mpw,
    const float* __restrict__ qkvw, const float* __restrict__ outw,
    const float* __restrict__ fw1,  const float* __restrict__ fw2,
    const float* __restrict__ cw1,
    ushort_t* ipwT, ushort_t* mpwT, ushort_t* qkvT, ushort_t* outwT,
    ushort_t* fw1T, ushort_t* fw2T, ushort_t* cw1T,
    const float* __restrict__ convw, ushort_t* wrepT,
    const float* __restrict__ bg, const float* __restrict__ bb,
    const float* __restrict__ rm, const float* __restrict__ rv,
    float* bnsc, float* bnsh,
    ushort_t* h448g, const float* __restrict__ clstok, float* h449,
    const float* __restrict__ ln1g0, const float* __restrict__ ln1b0,
    ushort_t* clsY)
{
    __shared__ float redp[4];
    const int bid = blockIdx.x;
    if (bid >= 3239) {                        // LN(cls_token) w/ layer-0 ln1 -> bufB2 cls rows
        const int d = threadIdx.x;
        float v = clstok[d];
        float s = v;
        #pragma unroll
        for (int o = 32; o > 0; o >>= 1) s += __shfl_down(s, o, 64);
        if ((d & 63) == 0) redp[d >> 6] = s;
        __syncthreads();
        float mean = (redp[0] + redp[1] + redp[2] + redp[3]) * (1.f / 256.f);
        __syncthreads();
        float diff = v - mean;
        float s2 = diff * diff;
        #pragma unroll
        for (int o = 32; o > 0; o >>= 1) s2 += __shfl_down(s2, o, 64);
        if ((d & 63) == 0) redp[d >> 6] = s2;
        __syncthreads();
        float rstd = rsqrtf((redp[0] + redp[1] + redp[2] + redp[3]) * (1.f / 256.f) + 1e-5f);
        ushort_t y = f2bf(diff * rstd * ln1g0[d] + ln1b0[d]);
        for (int b = 0; b < BB; ++b)
            clsY[(size_t)(b * TFRONT) * 256 + d] = y;
        return;
    }
    if (bid >= 3175) {                        // cls-token copy into h449 row 0
        int b = bid - 3175;
        h449[(size_t)b * TTT * 256 + threadIdx.x] = clstok[threadIdx.x];
        return;
    }
    if (bid >= 3111) {                        // zero guard rows of h448g
        int b = bid - 3111;
        #pragma unroll
        for (int j = 0; j < 8; ++j)
            h448g[(size_t)(b * GROWS + j) * 256 + threadIdx.x] = 0;
        return;
    }
    if (bid >= 3108) {                        // BN folding
        int i = (bid - 3108) * 256 + threadIdx.x;
        if (i < 768) {
            float sc = rsqrtf(rv[i] + 1e-5f) * bg[i];
            bnsc[i] = sc;
            bnsh[i] = bb[i] - rm[i] * sc;
        }
        return;
    }
    if (bid >= 804) {                         // conv weight repack
        int i = (bid - 804) * 256 + threadIdx.x;
        int s = i / 196608; int o = i - s * 196608;
        int ci = o & 255; int t3 = (o >> 8) % 3; int co = o / 768;
        wrepT[i] = f2bf(convw[(((size_t)s * 256 + co) * 256 + ci) * 3 + t3]);
        return;
    }
    const float* src; ushort_t* dst; int K, N, local;
    if (bid < 4)        { src = ipw;  dst = ipwT;  K = 64;   N = 256;  local = bid; }
    else if (bid < 20)  { src = mpw;  dst = mpwT;  K = 256;  N = 256;  local = bid - 4; }
    else if (bid < 212) { int l = bid - 20;  int z = l / 48; l -= z * 48;
                          src = qkvw + (size_t)z * 196608; dst = qkvT + (size_t)z * 196608;
                          K = 256;  N = 768;  local = l; }
    else if (bid < 276) { int l = bid - 212; int z = l / 16; l -= z * 16;
                          src = outw + (size_t)z * 65536;  dst = outwT + (size_t)z * 65536;
                          K = 256;  N = 256;  local = l; }
    else if (bid < 532) { int l = bid - 276; int z = l / 64; l -= z * 64;
                          src = fw1 + (size_t)z * 262144;  dst = fw1T + (size_t)z * 262144;
                          K = 256;  N = 1024; local = l; }
    else if (bid < 788) { int l = bid - 532; int z = l / 64; l -= z * 64;
                          src = fw2 + (size_t)z * 262144;  dst = fw2T + (size_t)z * 262144;
                          K = 1024; N = 256;  local = l; }
    else                { src = cw1;  dst = cw1T;  K = 256;  N = 256;  local = bid - 788; }

    __shared__ float tile[64][65];
    int nt = N / 64;
    int n0 = (local % nt) * 64, k0 = (local / nt) * 64;
    int tx = threadIdx.x & 63, ty = threadIdx.x >> 6;
    #pragma unroll
    for (int i = 0; i < 16; ++i)
        tile[i * 4 + ty][tx] = src[(size_t)(k0 + i * 4 + ty) * N + n0 + tx];
    __syncthreads();
    #pragma unroll
    for (int i = 0; i < 16; ++i) {
        int n = i * 4 + ty;
        dst[(size_t)(n0 + n) * K + k0 + tx] = f2bf(tile[tx][n]);
    }
}

// ---------------- gate softmax + fuse, wave-per-row ----------------
__global__ __launch_bounds__(256) void gate_fuse(
    const ushort_t* __restrict__ conv,  // [3][Mrows][256]
    const float* __restrict__ gw, const float* __restrict__ gb,
    ushort_t* __restrict__ fused, int Mrows)
{
    const int w = threadIdx.x >> 6, lane = threadIdx.x & 63;
    const int m = blockIdx.x * 4 + w;
    const int d0 = lane * 4;
    float vals[3][4];
    float p0 = 0.f, p1 = 0.f, p2 = 0.f;
    #pragma unroll
    for (int s = 0; s < 3; ++s) {
        uint2 pk = *(const uint2*)&conv[((size_t)s * Mrows + m) * 256 + d0];
        vals[s][0] = bf2f(pk.x & 0xffff); vals[s][1] = bf2f(pk.x >> 16);
        vals[s][2] = bf2f(pk.y & 0xffff); vals[s][3] = bf2f(pk.y >> 16);
        #pragma unroll
        for (int e = 0; e < 4; ++e) {
            const float* wp = gw + (size_t)(s * 256 + d0 + e) * 3;
            float v = vals[s][e];
            p0 += v * wp[0]; p1 += v * wp[1]; p2 += v * wp[2];
        }
    }
    #pragma unroll
    for (int o = 32; o > 0; o >>= 1) {
        p0 += __shfl_xor(p0, o); p1 += __shfl_xor(p1, o); p2 += __shfl_xor(p2, o);
    }
    float l0 = p0 + gb[0], l1 = p1 + gb[1], l2 = p2 + gb[2];
    float mx = fmaxf(l0, fmaxf(l1, l2));
    float e0 = __expf(l0 - mx), e1 = __expf(l1 - mx), e2 = __expf(l2 - mx);
    float inv = 1.f / (e0 + e1 + e2);
    float g0 = e0 * inv, g1 = e1 * inv, g2 = e2 * inv;
    unsigned r0 = pack2bf(vals[0][0] * g0 + vals[1][0] * g1 + vals[2][0] * g2,
                          vals[0][1] * g0 + vals[1][1] * g1 + vals[2][1] * g2);
    unsigned r1 = pack2bf(vals[0][2] * g0 + vals[1][2] * g1 + vals[2][2] * g2,
                          vals[0][3] * g0 + vals[1][3] * g1 + vals[2][3] * g2);
    *(uint2*)&fused[(size_t)m * 256 + d0] = make_uint2(r0, r1);
}

// ---------------- attention v8b: compact strides, window [qb-32, qb+47] ------
#define KP    480
#define KPAD  36
#define VPAD  488
#define PTPAD 40
__global__ __launch_bounds__(256, 2) void attn8_kernel(
    const ushort_t* __restrict__ qkv,
    const float* __restrict__ alpha,
    ushort_t* __restrict__ O,
    int kst, int nqt, int ost)
{
    __shared__ ushort_t sK[KP][KPAD];
    __shared__ ushort_t sVt[32][VPAD];
    __shared__ ushort_t sPT[4][16][PTPAD];
    __shared__ float sRed[4];

    const int bh = blockIdx.x;
    const int b = bh >> 3, h = bh & 7;
    const int tid = threadIdx.x;
    const int w = tid >> 6, lane = tid & 63;
    const int l15 = lane & 15, quad = lane >> 4;
    const float LOG2E = 1.4426950408889634f;
    const float scale2 = 0.17677669529663687f * LOG2E;

    float av = alpha[h];
    float a_sp = (av > 20.f) ? av : log1pf(__expf(av));
    const float a_h = a_sp * LOG2E;

    {
        int r0 = tid >> 2, c = (tid & 3) * 8;
        float knmax = 0.f;
        for (int r = r0; r < kst; r += 64) {
            const ushort_t* src = qkv + ((size_t)(b * kst + r)) * 768 + 256 + h * 32 + c;
            short8 kv = *(const short8*)src;
            short8 vv = *(const short8*)(src + 256);
            *(short8*)&sK[r][c] = kv;
            float ssq = 0.f;
            #pragma unroll
            for (int j = 0; j < 8; ++j) {
                float kf = bf2f(((const ushort_t*)&kv)[j]);
                ssq += kf * kf;
                sVt[c + j][r] = ((const ushort_t*)&vv)[j];
            }
            ssq += __shfl_xor(ssq, 1);
            ssq += __shfl_xor(ssq, 2);
            knmax = fmaxf(knmax, ssq);
        }
        #pragma unroll
        for (int o = 32; o > 0; o >>= 1) knmax = fmaxf(knmax, __shfl_xor(knmax, o));
        if (lane == 0) sRed[w] = knmax;
    }
    __syncthreads();
    const float kmax2 = fmaxf(fmaxf(sRed[0], sRed[1]), fmaxf(sRed[2], sRed[3]));

    for (int qt = w; qt < nqt; qt += 4) {
        const int qb = qt * 16;
        const int qrow = qb + l15;
        short8 qfrag = *(const short8*)(qkv + ((size_t)(b * kst + qrow)) * 768 + h * 32 + quad * 8);
        const f32x4 z = {0.f, 0.f, 0.f, 0.f};

        float qn = 0.f;
        #pragma unroll
        for (int j = 0; j < 8; ++j) { float f = bf2f(qfrag[j]); qn += f * f; }
        qn += __shfl_xor(qn, 16);
        qn += __shfl_xor(qn, 32);
        const float Mr = scale2 * sqrtf(qn * kmax2);
        const float fq = (float)qrow;

        int ch_lo = (qb - 32) >> 5; if (ch_lo < 0) ch_lo = 0;
        int ch_hi = (qb + 47) >> 5;
        const int ch_max = (kst >> 5) - 1;
        if (ch_hi > ch_max) ch_hi = ch_max;

        f32x4 o0 = z, o1 = z;
        float lsum = 0.f;
        for (int ch = ch_lo; ch <= ch_hi; ++ch) {
            const int kb = ch * 32;
            short8 kf0 = *(const short8*)&sK[kb + l15][quad * 8];
            short8 kf1 = *(const short8*)&sK[kb + 16 + l15][quad * 8];
            f32x4 s0 = __builtin_amdgcn_mfma_f32_16x16x32_bf16(kf0, qfrag, z, 0, 0, 0);
            f32x4 s1 = __builtin_amdgcn_mfma_f32_16x16x32_bf16(kf1, qfrag, z, 0, 0, 0);
            float p0[4], p1[4];
            #pragma unroll
            for (int r = 0; r < 4; ++r) {
                int k0 = kb + quad * 4 + r;
                int k1 = k0 + 16;
                float b0 = s0[r] * scale2 - (a_h * fabsf(fq - (float)k0) + Mr);
                float b1 = s1[r] * scale2 - (a_h * fabsf(fq - (float)k1) + Mr);
                p0[r] = exp2f(b0);
                p1[r] = exp2f(b1);
            }
            lsum += (p0[0] + p0[1]) + (p0[2] + p0[3]) + (p1[0] + p1[1]) + (p1[2] + p1[3]);
            unsigned* prow = (unsigned*)&sPT[w][l15][0];
            prow[quad * 2]     = pack2bf(p0[0], p0[1]);
            prow[quad * 2 + 1] = pack2bf(p0[2], p0[3]);
            prow[8 + quad * 2]     = pack2bf(p1[0], p1[1]);
            prow[8 + quad * 2 + 1] = pack2bf(p1[2], p1[3]);
            short8 pB = *(const short8*)&sPT[w][l15][quad * 8];
            short8 v0 = *(const short8*)&sVt[l15][kb + quad * 8];
            short8 v1 = *(const short8*)&sVt[16 + l15][kb + quad * 8];
            o0 = __builtin_amdgcn_mfma_f32_16x16x32_bf16(v0, pB, o0, 0, 0, 0);
            o1 = __builtin_amdgcn_mfma_f32_16x16x32_bf16(v1, pB, o1, 0, 0, 0);
        }
        lsum += __shfl_xor(lsum, 16);
        lsum += __shfl_xor(lsum, 32);

        {
            float inv = 1.f / lsum;
            unsigned* dst = (unsigned*)&O[((size_t)(b * ost + qrow)) * 256 + h * 32 + quad * 4];
            dst[0] = pack2bf(o0[0] * inv, o0[1] * inv);
            dst[1] = pack2bf(o0[2] * inv, o0[3] * inv);
            dst[8] = pack2bf(o1[0] * inv, o1[1] * inv);
            dst[9] = pack2bf(o1[2] * inv, o1[3] * inv);
        }
    }
}

// ---------------- fused head: final LN + cls MLP + logit (1 block/batch) -----
__global__ __launch_bounds__(256) void head_kernel(
    const float* __restrict__ h449,
    const float* __restrict__ fing, const float* __restrict__ finb,
    const ushort_t* __restrict__ cw1T, const float* __restrict__ cb1,
    const float* __restrict__ cw2, const float* __restrict__ b2,
    float* __restrict__ out)
{
    __shared__ float xn[256];
    __shared__ float red[4];
    const int b = blockIdx.x, d = threadIdx.x;
    float v = h449[(size_t)b * TTT * 256 + d];
    float s = v;
    #pragma unroll
    for (int o = 32; o > 0; o >>= 1) s += __shfl_down(s, o, 64);
    if ((d & 63) == 0) red[d >> 6] = s;
    __syncthreads();
    float mean = (red[0] + red[1] + red[2] + red[3]) * (1.f / 256.f);
    __syncthreads();
    float diff = v - mean;
    float s2 = diff * diff;
    #pragma unroll
    for (int o = 32; o > 0; o >>= 1) s2 += __shfl_down(s2, o, 64);
    if ((d & 63) == 0) red[d >> 6] = s2;
    __syncthreads();
    float rstd = rsqrtf((red[0] + red[1] + red[2] + red[3]) * (1.f / 256.f) + 1e-5f);
    xn[d] = diff * rstd * fing[d] + finb[d];
    __syncthreads();
    const ushort_t* wrow = cw1T + (size_t)d * 256;
    float acc = 0.f;
    #pragma unroll 4
    for (int k = 0; k < 256; k += 8) {
        short8 wv = *(const short8*)&wrow[k];
        #pragma unroll
        for (int j = 0; j < 8; ++j) acc += xn[k + j] * bf2f(((const ushort_t*)&wv)[j]);
    }
    float p = gelu_f(acc + cb1[d]) * cw2[d];
    #pragma unroll
    for (int o = 32; o > 0; o >>= 1) p += __shfl_down(p, o, 64);
    __syncthreads();
    if ((d & 63) == 0) red[d >> 6] = p;
    __syncthreads();
    if (d == 0) out[b] = red[0] + red[1] + red[2] + red[3] + b2[0];
}

// ---------------- orchestration ----------------
extern "C" void kernel_launch(void* const* d_in, const int* in_sizes, int n_in,
                              void* d_out, int out_size, void* d_ws, size_t ws_size,
                              hipStream_t stream)
{
    const float* x      = (const float*)d_in[0];
    const float* ipw    = (const float*)d_in[1];
    const float* ipb    = (const float*)d_in[2];
    const float* convw  = (const float*)d_in[3];
    const float* convb  = (const float*)d_in[4];
    const float* bng    = (const float*)d_in[5];
    const float* bnb    = (const float*)d_in[6];
    const float* bnrm   = (const float*)d_in[7];
    const float* bnrv   = (const float*)d_in[8];
    const float* gatew  = (const float*)d_in[9];
    const float* gateb  = (const float*)d_in[10];
    const float* mpw    = (const float*)d_in[11];
    const float* mpb    = (const float*)d_in[12];
    const float* clstok = (const float*)d_in[13];
    const float* qkvw   = (const float*)d_in[14];
    const float* qkvb   = (const float*)d_in[15];
    const float* outw   = (const float*)d_in[16];
    const float* outb   = (const float*)d_in[17];
    const float* alpha  = (const float*)d_in[18];
    const float* ln1g   = (const float*)d_in[19];
    const float* ln1b   = (const float*)d_in[20];
    const float* ln2g   = (const float*)d_in[21];
    const float* ln2b   = (const float*)d_in[22];
    const float* fw1    = (const float*)d_in[23];
    const float* fb1    = (const float*)d_in[24];
    const float* fw2    = (const float*)d_in[25];
    const float* fb2    = (const float*)d_in[26];
    const float* fing   = (const float*)d_in[27];
    const float* finb   = (const float*)d_in[28];
    const float* cw1    = (const float*)d_in[29];
    const float* cb1    = (const float*)d_in[30];
    const float* cw2    = (const float*)d_in[31];
    const float* cb2    = (const float*)d_in[32];

    const int KL[4] = {160, 128, 96, 64};
    const int QL[4] = {128, 96, 64, 16};

    // ---- workspace layout ----
    char* base = (char*)d_ws;
    size_t off = 0;
    auto alloc = [&](size_t bytes) { char* p = base + off; off += (bytes + 255) & ~(size_t)255; return p; };
    float*    h448  = (float*)alloc((size_t)MFRONT * 256 * 4);
    float*    h449  = (float*)alloc((size_t)MPAD * 256 * 4);
    float*    bufA  = (float*)alloc((size_t)MFRONT * 768 * 4);
    ushort_t* conv_bf = (ushort_t*)bufA;
    ushort_t* qkv_bf  = (ushort_t*)bufA;
    ushort_t* bufMid  = (ushort_t*)bufA;
    ushort_t* bufB  = (ushort_t*)alloc((size_t)MFRONT * 256 * 2);
    ushort_t* bufB2 = (ushort_t*)alloc((size_t)MFRONT * 256 * 2);
    ushort_t* bufC  = (ushort_t*)alloc((size_t)64 * 128 * 256 * 2);
    ushort_t* h448g = (ushort_t*)alloc((size_t)BB * GROWS * 256 * 2);
    ushort_t* wrepT = (ushort_t*)alloc((size_t)3 * 256 * 768 * 2);
    ushort_t* ipwT  = (ushort_t*)alloc((size_t)64 * 256 * 2);
    ushort_t* mpwT  = (ushort_t*)alloc((size_t)256 * 256 * 2);
    ushort_t* qkvT  = (ushort_t*)alloc((size_t)4 * 768 * 256 * 2);
    ushort_t* outwT = (ushort_t*)alloc((size_t)4 * 256 * 256 * 2);
    ushort_t* fw1T  = (ushort_t*)alloc((size_t)4 * 1024 * 256 * 2);
    ushort_t* fw2T  = (ushort_t*)alloc((size_t)4 * 256 * 1024 * 2);
    ushort_t* cw1T  = (ushort_t*)alloc((size_t)256 * 256 * 2);
    float*    bnsc  = (float*)alloc(768 * 4);
    float*    bnsh  = (float*)alloc(768 * 4);

    auto gemm = [&](const ushort_t* A, const ushort_t* Bt, void* C, ushort_t* C2,
                    const float* bias, const float* scl, const float* shf, const float* R,
                    int M, int N, int K, int a_dil, int gelu_fl, int omode, int pemode,
                    int rc_mod = 0, int gz = 1) {
        dim3 grid(N / 128, M / 128, gz);
        hipLaunchKernelGGL(gemm_bf16, grid, dim3(256), 0, stream,
                           A, Bt, C, C2, bias, scl, shf, R, M, N, K, a_dil, gelu_fl,
                           omode, pemode, rc_mod);
    };
    auto gemmln = [&](const ushort_t* A, const ushort_t* Bt, float* C, ushort_t* Yp,
                      const float* bias, const float* R,
                      const float* g, const float* b,
                      int M, int K, int pemode, int rcm) {
        hipLaunchKernelGGL(gemm_ln, dim3(1, M / 64), dim3(256), 0, stream,
                           A, Bt, C, Yp, bias, R, g, b, M, K, pemode, rcm);
    };

    // ---- prep: transposes + conv repack + BN + guard zero + cls copy/LN ----
    hipLaunchKernelGGL(prep_all, dim3(3240), dim3(256), 0, stream,
                       ipw, mpw, qkvw, outw, fw1, fw2, cw1,
                       ipwT, mpwT, qkvT, outwT, fw1T, fw2T, cw1T,
                       convw, wrepT, bng, bnb, bnrm, bnrv, bnsc, bnsh,
                       h448g, clstok, h449, ln1g, ln1b, bufB2);

    // ---- input projection on rows t<160: h448 f32 + h448g bf16 (guarded) ----
    gemm((const ushort_t*)x, ipwT, h448, h448g, ipb, nullptr, nullptr, nullptr,
         MFRONT, 256, 64, -2, 0, 2, 0);

    // ---- conv (3 scales in z), DMA staging from h448g, fused gelu+BN ----
    gemm(h448g, wrepT, conv_bf, nullptr, convb, bnsc, bnsh, nullptr,
         MFRONT, 256, 768, -1, 1, 1, 0, 0, 3);
    hipLaunchKernelGGL(gate_fuse, dim3(MFRONT / 4), dim3(256), 0, stream,
                       conv_bf, gatew, gateb, bufB, MFRONT);
    // ms_proj + residual + PE -> h449 rows 1..160; fused LN1(l0) -> bufB2
    gemmln(bufB, mpwT, h449, bufB2, mpb, h448, ln1g, ln1b,
           MFRONT, 256, 1, 0);

    // ---- transformer layers on the shrinking cone ----
    for (int l = 0; l < LAYERS; ++l) {
        const int Kl = KL[l], Ql = QL[l];
        const int MK = 64 * Kl, MQ = 64 * Ql;
        gemm(bufB2, qkvT + (size_t)l * 768 * 256, qkv_bf, nullptr, qkvb + l * 768,
             nullptr, nullptr, nullptr, MK, 768, 256, 0, 0, 1, 0);
        hipLaunchKernelGGL(attn8_kernel, dim3(BB * HEADS), dim3(256), 0, stream,
                           qkv_bf, alpha + l * HEADS, bufC, Kl, Ql / 16, Ql);
        // out-proj + residual -> h449 ; fused LN2(l) -> bufB2
        gemmln(bufC, outwT + (size_t)l * 65536, h449, bufB2, outb + l * 256,
               h449, ln2g + l * 256, ln2b + l * 256, MQ, 256, 0, Ql);
        gemm(bufB2, fw1T + (size_t)l * 262144, bufMid, nullptr, fb1 + l * 1024,
             nullptr, nullptr, nullptr, MQ, 1024, 256, 0, 1, 1, 0);
        // ffn2 + residual -> h449 ; fused LN1(l+1) -> bufB2 (skip on last layer)
        gemmln(bufMid, fw2T + (size_t)l * 262144, h449,
               (l < 3) ? bufB2 : nullptr, fb2 + l * 256, h449,
               (l < 3) ? ln1g + (l + 1) * 256 : nullptr,
               (l < 3) ? ln1b + (l + 1) * 256 : nullptr,
               MQ, 1024, 0, Ql);
    }

    // ---- fused head: final LN + cls MLP + logit ----
    hipLaunchKernelGGL(head_kernel, dim3(BB), dim3(256), 0, stream,
                       h449, fing, finb, cw1T, cb1, cw2, cb2, (float*)d_out);
}

// Round 8
// 536.465 us; speedup vs baseline: 1.0880x; 1.0035x over previous
//
#include <hip/hip_runtime.h>
#include <hip/hip_bf16.h>
#include <math.h>

// ---------------- model constants ----------------
#define BB   64
#define TT   448
#define TTT  449
#define DIM  256
#define HEADS 8
#define HD   32
#define LAYERS 4
#define FFD  1024
#define INDIM 64
#define MPAD 28800
// dependency cone (window [qb-32, qb+47], chunk-granular):
#define TFRONT 160            // front-end rows/batch
#define MFRONT (BB*TFRONT)    // 10240
#define GROWS  168            // guarded rows/batch in h448g (8 zero + 160)

typedef __attribute__((ext_vector_type(8))) short short8;
typedef __attribute__((ext_vector_type(4))) float f32x4;
typedef unsigned short ushort_t;

__device__ __forceinline__ float gelu_f(float x) {
    float x2 = x * x;
    float m = 0.10295219f * x2 + 2.3022635f;
    float t = exp2f(-x * m);
    return x * (1.f / (1.f + t));
}
__device__ __forceinline__ ushort_t f2bf(float x) {
    unsigned u; __builtin_memcpy(&u, &x, 4);
    return (ushort_t)((u + 0x8000u) >> 16);
}
__device__ __forceinline__ unsigned pack2bf(float a, float b) {
    unsigned ua, ub;
    __builtin_memcpy(&ua, &a, 4); __builtin_memcpy(&ub, &b, 4);
    return ((ua + 0x8000u) >> 16) | ((ub + 0x8000u) & 0xffff0000u);
}
__device__ __forceinline__ float bf2f(ushort_t u) {
    unsigned v = ((unsigned)u) << 16; float f; __builtin_memcpy(&f, &v, 4); return f;
}
__device__ __forceinline__ void gload16(const ushort_t* g, ushort_t* l) {
    __builtin_amdgcn_global_load_lds(
        (const __attribute__((address_space(1))) void*)g,
        (__attribute__((address_space(3))) void*)l, 16, 0, 0);
}

// ---------------- bf16 MFMA GEMM v7 (R12 structure) ----------------
// C[m,n] = sum_k A[m,k] * Bt[n,k]
// a_dil > 0 : conv mode — A is guard-padded h448g [b*168 + 8 + t], t=gm%160.
// a_dil == -1: merged conv (blockIdx.z selects scale s: a_dil=1<<s).
// a_dil == -2: A is f32 x [b*448 + t] (t=gm%160); C2 written to h448g layout.
// rc_mod > 0: R and C row = (gm/rc_mod)*449 + gm%rc_mod (h449 layout).
// pe_mode: C row = (gm/160)*449 + 1 + gm%160, add sinusoidal PE (f32 out).
__global__ __launch_bounds__(256, 3) void gemm_bf16(
    const ushort_t* __restrict__ A, const ushort_t* __restrict__ Bt,
    void* __restrict__ C, ushort_t* __restrict__ C2,
    const float* __restrict__ bias,
    const float* __restrict__ scalev, const float* __restrict__ shiftv,
    const float* __restrict__ R,
    int M, int N, int K, int a_dil, int do_gelu, int out_mode, int pe_mode,
    int rc_mod)
{
    __shared__ ushort_t smem[2 * 128 * 64];
    ushort_t* As = smem;
    ushort_t* Bs = smem + 128 * 64;
    const int tid = threadIdx.x;
    const int lane = tid & 63, w = tid >> 6;
    const int wm = w >> 1, wn = w & 1;
    const int l15 = lane & 15, quad = lane >> 4;
    const int m0 = blockIdx.y * 128, n0 = blockIdx.x * 128;
    const int sr = lane >> 3, ss = lane & 7;
    const int gsw = ss ^ sr;

    if (a_dil == -1) {                 // merged conv dispatch
        int z = blockIdx.z;
        a_dil = 1 << z;
        Bt += (size_t)z * 196608;
        C = (void*)((ushort_t*)C + (size_t)z * MFRONT * 256);
        bias += z * 256; scalev += z * 256; shiftv += z * 256;
    }
    const ushort_t* aconv[4];
    if (a_dil > 0) {
        #pragma unroll
        for (int j = 0; j < 4; ++j) {
            int r = (w * 4 + j) * 8 + sr;
            int gm = m0 + r;
            int b = gm / TFRONT, t = gm - b * TFRONT;
            aconv[j] = A + ((size_t)(b * GROWS + 8 + t)) * 256 + gsw * 8;
        }
    }
    f32x4 acc[4][4] = {};

    for (int k0 = 0; k0 < K; k0 += 64) {
        if (a_dil > 0) {
            int tap = k0 >> 8;
            int aoff = (k0 & 255) - ((2 - tap) * a_dil) * 256;
            #pragma unroll
            for (int j = 0; j < 4; ++j)
                gload16(aconv[j] + aoff, &As[(w * 4 + j) * 512]);
        } else if (a_dil == -2) {
            const float* Af = (const float*)A;
            #pragma unroll
            for (int j = 0; j < 4; ++j) {
                int r = (w * 4 + j) * 8 + sr;
                int gm = m0 + r;
                int b = gm / TFRONT, t = gm - b * TFRONT;
                const float* ap = Af + ((size_t)b * 448 + t) * K + k0 + gsw * 8;
                float4 a0 = *(const float4*)ap;
                float4 a1 = *(const float4*)(ap + 4);
                uint2 lo = make_uint2(pack2bf(a0.x, a0.y), pack2bf(a0.z, a0.w));
                uint2 hi = make_uint2(pack2bf(a1.x, a1.y), pack2bf(a1.z, a1.w));
                *(uint2*)&As[r * 64 + ss * 8] = lo;
                *(uint2*)&As[r * 64 + ss * 8 + 4] = hi;
            }
        } else {
            #pragma unroll
            for (int j = 0; j < 4; ++j) {
                int r = (w * 4 + j) * 8 + sr;
                int g = ss ^ (r & 7);
                gload16(&A[(size_t)(m0 + r) * K + k0 + g * 8], &As[(w * 4 + j) * 512]);
            }
        }
        #pragma unroll
        for (int j = 0; j < 4; ++j) {
            int r = (w * 4 + j) * 8 + sr;
            int g = ss ^ (r & 7);
            gload16(&Bt[(size_t)(n0 + r) * K + k0 + g * 8], &Bs[(w * 4 + j) * 512]);
        }
        __syncthreads();
        #pragma unroll
        for (int ks = 0; ks < 2; ++ks) {
            short8 af[4], bfr[4];
            #pragma unroll
            for (int i = 0; i < 4; ++i) {
                int row = wm * 64 + i * 16 + l15;
                af[i] = *(const short8*)&As[row * 64 + (((ks * 4 + quad) ^ (l15 & 7)) * 8)];
            }
            #pragma unroll
            for (int j = 0; j < 4; ++j) {
                int row = wn * 64 + j * 16 + l15;
                bfr[j] = *(const short8*)&Bs[row * 64 + (((ks * 4 + quad) ^ (l15 & 7)) * 8)];
            }
            #pragma unroll
            for (int i = 0; i < 4; ++i)
                #pragma unroll
                for (int j = 0; j < 4; ++j)
                    acc[i][j] = __builtin_amdgcn_mfma_f32_16x16x32_bf16(
                        af[i], bfr[j], acc[i][j], 0, 0, 0);
        }
        __syncthreads();
    }

    // ---- vectorized epilogue via per-wave LDS transpose ----
    float* wreg = (float*)smem + w * 2048;
    const int gn0 = n0 + wn * 64 + l15 * 4;
    float4 bias4 = bias ? *(const float4*)&bias[gn0] : make_float4(0.f, 0.f, 0.f, 0.f);
    float4 scl4, shf4;
    if (scalev) { scl4 = *(const float4*)&scalev[gn0]; shf4 = *(const float4*)&shiftv[gn0]; }
    else        { scl4 = make_float4(1.f, 1.f, 1.f, 1.f); shf4 = make_float4(0.f, 0.f, 0.f, 0.f); }

    #pragma unroll
    for (int ci = 0; ci < 2; ++ci) {
        #pragma unroll
        for (int i2 = 0; i2 < 2; ++i2) {
            int i = ci * 2 + i2;
            #pragma unroll
            for (int j = 0; j < 4; ++j) {
                float* col = &wreg[(i2 * 16 + quad * 4) * 64 + j * 16 + l15];
                #pragma unroll
                for (int r = 0; r < 4; ++r) col[r * 64] = acc[i][j][r];
            }
        }
        #pragma unroll
        for (int rr = 0; rr < 8; ++rr) {
            int rl = rr * 4 + quad;
            float4 v = *(float4*)&wreg[rl * 64 + l15 * 4];
            int gm = m0 + wm * 64 + ci * 32 + rl;
            v.x += bias4.x; v.y += bias4.y; v.z += bias4.z; v.w += bias4.w;
            if (do_gelu) { v.x = gelu_f(v.x); v.y = gelu_f(v.y); v.z = gelu_f(v.z); v.w = gelu_f(v.w); }
            v.x = v.x * scl4.x + shf4.x; v.y = v.y * scl4.y + shf4.y;
            v.z = v.z * scl4.z + shf4.z; v.w = v.w * scl4.w + shf4.w;
            size_t crow = (size_t)gm;
            if (rc_mod > 0) crow = (size_t)(gm / rc_mod) * 449 + (gm % rc_mod);
            if (R) {
                float4 r4 = *(const float4*)&R[crow * N + gn0];
                v.x += r4.x; v.y += r4.y; v.z += r4.z; v.w += r4.w;
            }
            if (pe_mode) {
                int bi = gm / TFRONT, t = gm - bi * TFRONT;
                float ft = (float)t;
                float f0 = __expf(-9.210340371976184f * (float)gn0 * (1.f / 256.f));
                float f1 = __expf(-9.210340371976184f * (float)(gn0 + 2) * (1.f / 256.f));
                float a0 = ft * f0, a1 = ft * f1;
                v.x += __sinf(a0); v.y += __cosf(a0);
                v.z += __sinf(a1); v.w += __cosf(a1);
                *(float4*)&((float*)C)[(size_t)(bi * 449 + 1 + t) * 256 + gn0] = v;
            } else if (out_mode == 1) {
                uint2 pk = make_uint2(pack2bf(v.x, v.y), pack2bf(v.z, v.w));
                *(uint2*)&((ushort_t*)C)[crow * N + gn0] = pk;
            } else {
                *(float4*)&((float*)C)[crow * N + gn0] = v;
                if (out_mode == 2) {
                    int bi = gm / TFRONT, t = gm - bi * TFRONT;
                    size_t grow = (size_t)(bi * GROWS + 8 + t);
                    uint2 pk = make_uint2(pack2bf(v.x, v.y), pack2bf(v.z, v.w));
                    *(uint2*)&C2[grow * N + gn0] = pk;
                }
            }
        }
    }
}

// ---------------- bf16 MFMA GEMM + fused LayerNorm (N=256 full-row tile) ----
// Tile 64x256, 4 waves (each 64 rows x 64-col slice). Epilogue v2:
// - residual loads hoisted (one latency exposure per ci)
// - v held in registers across the stats phase (no LDS re-read passes)
// - one-pass mean/var (E[x^2] - m^2)
// - dedicated shared scratch (no aliasing with the wreg transpose buffer)
// - 2 barriers per ci (4 total)
// pe_mode: C row = b*449+1+t, Y row = gm+1 (skip t==159).
// Y==null: skip LN output (ffn2 of last layer).
__global__ __launch_bounds__(256, 3) void gemm_ln(
    const ushort_t* __restrict__ A, const ushort_t* __restrict__ Bt,
    float* __restrict__ C, ushort_t* __restrict__ Y,
    const float* __restrict__ bias, const float* __restrict__ R,
    const float* __restrict__ lng, const float* __restrict__ lnb,
    int M, int K, int pe_mode, int rc_mod)
{
    __shared__ __align__(16) char smraw[40960];
    __shared__ float sred[2][32][4];
    __shared__ float smean[32];
    __shared__ float srstd[32];
    ushort_t* As = (ushort_t*)smraw;
    ushort_t* Bs = (ushort_t*)(smraw + 8192);
    const int tid = threadIdx.x;
    const int lane = tid & 63, w = tid >> 6;
    const int l15 = lane & 15, quad = lane >> 4;
    const int m0 = blockIdx.y * 64;
    const int sr = lane >> 3, ss = lane & 7;
    const int gsw = ss ^ sr;

    f32x4 acc[4][4] = {};

    for (int k0 = 0; k0 < K; k0 += 64) {
        #pragma unroll
        for (int j = 0; j < 2; ++j) {
            int ch = w * 2 + j;
            gload16(&A[(size_t)(m0 + ch * 8 + sr) * K + k0 + gsw * 8], &As[ch * 512]);
        }
        #pragma unroll
        for (int j = 0; j < 8; ++j) {
            int ch = w * 8 + j;
            gload16(&Bt[(size_t)(ch * 8 + sr) * K + k0 + gsw * 8], &Bs[ch * 512]);
        }
        __syncthreads();
        #pragma unroll
        for (int ks = 0; ks < 2; ++ks) {
            short8 af[4], bfr[4];
            #pragma unroll
            for (int i = 0; i < 4; ++i) {
                int row = i * 16 + l15;
                af[i] = *(const short8*)&As[row * 64 + (((ks * 4 + quad) ^ (l15 & 7)) * 8)];
            }
            #pragma unroll
            for (int j = 0; j < 4; ++j) {
                int row = w * 64 + j * 16 + l15;
                bfr[j] = *(const short8*)&Bs[row * 64 + (((ks * 4 + quad) ^ (l15 & 7)) * 8)];
            }
            #pragma unroll
            for (int i = 0; i < 4; ++i)
                #pragma unroll
                for (int j = 0; j < 4; ++j)
                    acc[i][j] = __builtin_amdgcn_mfma_f32_16x16x32_bf16(
                        af[i], bfr[j], acc[i][j], 0, 0, 0);
        }
        __syncthreads();
    }

    // ---- epilogue v2 ----
    float* wreg = (float*)smraw + w * 2048;
    const int gn0 = w * 64 + l15 * 4;
    float4 bias4 = *(const float4*)&bias[gn0];
    float4 g4 = make_float4(0.f, 0.f, 0.f, 0.f), b4 = g4;
    if (Y) { g4 = *(const float4*)&lng[gn0]; b4 = *(const float4*)&lnb[gn0]; }
    float pf0 = 0.f, pf1 = 0.f;
    if (pe_mode) {
        pf0 = __expf(-9.210340371976184f * (float)gn0 * (1.f / 256.f));
        pf1 = __expf(-9.210340371976184f * (float)(gn0 + 2) * (1.f / 256.f));
    }

    #pragma unroll
    for (int ci = 0; ci < 2; ++ci) {
        // (a) per-wave transpose acc -> wreg (same-wave RAW, ordered by lgkmcnt)
        #pragma unroll
        for (int i2 = 0; i2 < 2; ++i2) {
            int i = ci * 2 + i2;
            #pragma unroll
            for (int j = 0; j < 4; ++j) {
                float* col = &wreg[(i2 * 16 + quad * 4) * 64 + j * 16 + l15];
                #pragma unroll
                for (int r = 0; r < 4; ++r) col[r * 64] = acc[i][j][r];
            }
        }
        // (b) hoisted residual loads: all 8 issued together, one latency exposure
        float4 rv[8];
        if (R) {
            #pragma unroll
            for (int rr = 0; rr < 8; ++rr) {
                int gm = m0 + ci * 32 + rr * 4 + quad;
                size_t crow = (size_t)gm;
                if (rc_mod > 0) crow = (size_t)(gm / rc_mod) * 449 + (gm % rc_mod);
                rv[rr] = *(const float4*)&R[crow * 256 + gn0];
            }
        }
        // (c) v = acc^T + bias (+R) (+PE), kept in registers; partial sums -> sred
        float4 v[8];
        #pragma unroll
        for (int rr = 0; rr < 8; ++rr) {
            int rl = rr * 4 + quad;
            float4 t4 = *(float4*)&wreg[rl * 64 + l15 * 4];
            t4.x += bias4.x; t4.y += bias4.y; t4.z += bias4.z; t4.w += bias4.w;
            if (R) { t4.x += rv[rr].x; t4.y += rv[rr].y; t4.z += rv[rr].z; t4.w += rv[rr].w; }
            if (pe_mode) {
                int gm = m0 + ci * 32 + rl;
                float ft = (float)(gm - (gm / TFRONT) * TFRONT);
                float a0 = ft * pf0, a1 = ft * pf1;
                t4.x += __sinf(a0); t4.y += __cosf(a0);
                t4.z += __sinf(a1); t4.w += __cosf(a1);
            }
            v[rr] = t4;
            float s  = (t4.x + t4.y) + (t4.z + t4.w);
            float s2 = (t4.x * t4.x + t4.y * t4.y) + (t4.z * t4.z + t4.w * t4.w);
            s  += __shfl_xor(s, 1);  s  += __shfl_xor(s, 2);
            s  += __shfl_xor(s, 4);  s  += __shfl_xor(s, 8);
            s2 += __shfl_xor(s2, 1); s2 += __shfl_xor(s2, 2);
            s2 += __shfl_xor(s2, 4); s2 += __shfl_xor(s2, 8);
            if (l15 == 0) { sred[0][rl][w] = s; sred[1][rl][w] = s2; }
        }
        __syncthreads();
        // (d) cross-wave reduce: mean + rstd in one shot
        if (tid < 32) {
            float sm = (sred[0][tid][0] + sred[0][tid][1]) +
                       (sred[0][tid][2] + sred[0][tid][3]);
            float sq = (sred[1][tid][0] + sred[1][tid][1]) +
                       (sred[1][tid][2] + sred[1][tid][3]);
            float m = sm * (1.f / 256.f);
            smean[tid] = m;
            srstd[tid] = rsqrtf(sq * (1.f / 256.f) - m * m + 1e-5f);
        }
        __syncthreads();
        // (e) write C (f32) + Y (bf16 LN) straight from registers
        #pragma unroll
        for (int rr = 0; rr < 8; ++rr) {
            int rl = rr * 4 + quad;
            int gm = m0 + ci * 32 + rl;
            float vx = v[rr].x, vy = v[rr].y, vz = v[rr].z, vw = v[rr].w;
            if (pe_mode) {
                int bi = gm / TFRONT, t = gm - bi * TFRONT;
                *(float4*)&C[(size_t)(bi * 449 + 1 + t) * 256 + gn0] =
                    make_float4(vx, vy, vz, vw);
                if (Y && t != TFRONT - 1) {
                    float m = smean[rl], rs = srstd[rl];
                    *(uint2*)&Y[(size_t)(gm + 1) * 256 + gn0] = make_uint2(
                        pack2bf((vx - m) * rs * g4.x + b4.x, (vy - m) * rs * g4.y + b4.y),
                        pack2bf((vz - m) * rs * g4.z + b4.z, (vw - m) * rs * g4.w + b4.w));
                }
            } else {
                size_t crow = (size_t)gm;
                if (rc_mod > 0) crow = (size_t)(gm / rc_mod) * 449 + (gm % rc_mod);
                *(float4*)&C[crow * 256 + gn0] = make_float4(vx, vy, vz, vw);
                if (Y) {
                    float m = smean[rl], rs = srstd[rl];
                    *(uint2*)&Y[(size_t)gm * 256 + gn0] = make_uint2(
                        pack2bf((vx - m) * rs * g4.x + b4.x, (vy - m) * rs * g4.y + b4.y),
                        pack2bf((vz - m) * rs * g4.z + b4.z, (vw - m) * rs * g4.w + b4.w));
                }
            }
        }
    }
}

// ---- prep: transposes + conv repack + BN + guards + cls copy + cls LN ------
__global__ __launch_bounds__(256) void prep_all(
    const float* __restrict__ ipw,  const float* __restrict__ mpw,
    const float* __restrict__ qkvw, const float* __restrict__ outw,
    const float* __restrict__ fw1,  const float* __restrict__ fw2,
    const float* __restrict__ cw1,
    ushort_t* ipwT, ushort_t* mpwT, ushort_t* qkvT, ushort_t* outwT,
    ushort_t* fw1T, ushort_t* fw2T, ushort_t* cw1T,
    const float* __restrict__ convw, ushort_t* wrepT,
    const float* __restrict__ bg, const float* __restrict__ bb,
    const float* __restrict__ rm, const float* __restrict__ rv,
    float* bnsc, float* bnsh,
    ushort_t* h448g, const float* __restrict__ clstok, float* h449,
    const float* __restrict__ ln1g0, const float* __restrict__ ln1b0,
    ushort_t* clsY)
{
    __shared__ float redp[4];
    const int bid = blockIdx.x;
    if (bid >= 3239) {                        // LN(cls_token) w/ layer-0 ln1 -> bufB2 cls rows
        const int d = threadIdx.x;
        float v = clstok[d];
        float s = v;
        #pragma unroll
        for (int o = 32; o > 0; o >>= 1) s += __shfl_down(s, o, 64);
        if ((d & 63) == 0) redp[d >> 6] = s;
        __syncthreads();
        float mean = (redp[0] + redp[1] + redp[2] + redp[3]) * (1.f / 256.f);
        __syncthreads();
        float diff = v - mean;
        float s2 = diff * diff;
        #pragma unroll
        for (int o = 32; o > 0; o >>= 1) s2 += __shfl_down(s2, o, 64);
        if ((d & 63) == 0) redp[d >> 6] = s2;
        __syncthreads();
        float rstd = rsqrtf((redp[0] + redp[1] + redp[2] + redp[3]) * (1.f / 256.f) + 1e-5f);
        ushort_t y = f2bf(diff * rstd * ln1g0[d] + ln1b0[d]);
        for (int b = 0; b < BB; ++b)
            clsY[(size_t)(b * TFRONT) * 256 + d] = y;
        return;
    }
    if (bid >= 3175) {                        // cls-token copy into h449 row 0
        int b = bid - 3175;
        h449[(size_t)b * TTT * 256 + threadIdx.x] = clstok[threadIdx.x];
        return;
    }
    if (bid >= 3111) {                        // zero guard rows of h448g
        int b = bid - 3111;
        #pragma unroll
        for (int j = 0; j < 8; ++j)
            h448g[(size_t)(b * GROWS + j) * 256 + threadIdx.x] = 0;
        return;
    }
    if (bid >= 3108) {                        // BN folding
        int i = (bid - 3108) * 256 + threadIdx.x;
        if (i < 768) {
            float sc = rsqrtf(rv[i] + 1e-5f) * bg[i];
            bnsc[i] = sc;
            bnsh[i] = bb[i] - rm[i] * sc;
        }
        return;
    }
    if (bid >= 804) {                         // conv weight repack
        int i = (bid - 804) * 256 + threadIdx.x;
        int s = i / 196608; int o = i - s * 196608;
        int ci = o & 255; int t3 = (o >> 8) % 3; int co = o / 768;
        wrepT[i] = f2bf(convw[(((size_t)s * 256 + co) * 256 + ci) * 3 + t3]);
        return;
    }
    const float* src; ushort_t* dst; int K, N, local;
    if (bid < 4)        { src = ipw;  dst = ipwT;  K = 64;   N = 256;  local = bid; }
    else if (bid < 20)  { src = mpw;  dst = mpwT;  K = 256;  N = 256;  local = bid - 4; }
    else if (bid < 212) { int l = bid - 20;  int z = l / 48; l -= z * 48;
                          src = qkvw + (size_t)z * 196608; dst = qkvT + (size_t)z * 196608;
                          K = 256;  N = 768;  local = l; }
    else if (bid < 276) { int l = bid - 212; int z = l / 16; l -= z * 16;
                          src = outw + (size_t)z * 65536;  dst = outwT + (size_t)z * 65536;
                          K = 256;  N = 256;  local = l; }
    else if (bid < 532) { int l = bid - 276; int z = l / 64; l -= z * 64;
                          src = fw1 + (size_t)z * 262144;  dst = fw1T + (size_t)z * 262144;
                          K = 256;  N = 1024; local = l; }
    else if (bid < 788) { int l = bid - 532; int z = l / 64; l -= z * 64;
                          src = fw2 + (size_t)z * 262144;  dst = fw2T + (size_t)z * 262144;
                          K = 1024; N = 256;  local = l; }
    else                { src = cw1;  dst = cw1T;  K = 256;  N = 256;  local = bid - 788; }

    __shared__ float tile[64][65];
    int nt = N / 64;
    int n0 = (local % nt) * 64, k0 = (local / nt) * 64;
    int tx = threadIdx.x & 63, ty = threadIdx.x >> 6;
    #pragma unroll
    for (int i = 0; i < 16; ++i)
        tile[i * 4 + ty][tx] = src[(size_t)(k0 + i * 4 + ty) * N + n0 + tx];
    __syncthreads();
    #pragma unroll
    for (int i = 0; i < 16; ++i) {
        int n = i * 4 + ty;
        dst[(size_t)(n0 + n) * K + k0 + tx] = f2bf(tile[tx][n]);
    }
}

// ---------------- gate softmax + fuse, wave-per-row ----------------
__global__ __launch_bounds__(256) void gate_fuse(
    const ushort_t* __restrict__ conv,  // [3][Mrows][256]
    const float* __restrict__ gw, const float* __restrict__ gb,
    ushort_t* __restrict__ fused, int Mrows)
{
    const int w = threadIdx.x >> 6, lane = threadIdx.x & 63;
    const int m = blockIdx.x * 4 + w;
    const int d0 = lane * 4;
    float vals[3][4];
    float p0 = 0.f, p1 = 0.f, p2 = 0.f;
    #pragma unroll
    for (int s = 0; s < 3; ++s) {
        uint2 pk = *(const uint2*)&conv[((size_t)s * Mrows + m) * 256 + d0];
        vals[s][0] = bf2f(pk.x & 0xffff); vals[s][1] = bf2f(pk.x >> 16);
        vals[s][2] = bf2f(pk.y & 0xffff); vals[s][3] = bf2f(pk.y >> 16);
        #pragma unroll
        for (int e = 0; e < 4; ++e) {
            const float* wp = gw + (size_t)(s * 256 + d0 + e) * 3;
            float v = vals[s][e];
            p0 += v * wp[0]; p1 += v * wp[1]; p2 += v * wp[2];
        }
    }
    #pragma unroll
    for (int o = 32; o > 0; o >>= 1) {
        p0 += __shfl_xor(p0, o); p1 += __shfl_xor(p1, o); p2 += __shfl_xor(p2, o);
    }
    float l0 = p0 + gb[0], l1 = p1 + gb[1], l2 = p2 + gb[2];
    float mx = fmaxf(l0, fmaxf(l1, l2));
    float e0 = __expf(l0 - mx), e1 = __expf(l1 - mx), e2 = __expf(l2 - mx);
    float inv = 1.f / (e0 + e1 + e2);
    float g0 = e0 * inv, g1 = e1 * inv, g2 = e2 * inv;
    unsigned r0 = pack2bf(vals[0][0] * g0 + vals[1][0] * g1 + vals[2][0] * g2,
                          vals[0][1] * g0 + vals[1][1] * g1 + vals[2][1] * g2);
    unsigned r1 = pack2bf(vals[0][2] * g0 + vals[1][2] * g1 + vals[2][2] * g2,
                          vals[0][3] * g0 + vals[1][3] * g1 + vals[2][3] * g2);
    *(uint2*)&fused[(size_t)m * 256 + d0] = make_uint2(r0, r1);
}

// ---------------- attention v8b: compact strides, window [qb-32, qb+47] ------
#define KP    480
#define KPAD  36
#define VPAD  488
#define PTPAD 40
__global__ __launch_bounds__(256, 2) void attn8_kernel(
    const ushort_t* __restrict__ qkv,
    const float* __restrict__ alpha,
    ushort_t* __restrict__ O,
    int kst, int nqt, int ost)
{
    __shared__ ushort_t sK[KP][KPAD];
    __shared__ ushort_t sVt[32][VPAD];
    __shared__ ushort_t sPT[4][16][PTPAD];
    __shared__ float sRed[4];

    const int bh = blockIdx.x;
    const int b = bh >> 3, h = bh & 7;
    const int tid = threadIdx.x;
    const int w = tid >> 6, lane = tid & 63;
    const int l15 = lane & 15, quad = lane >> 4;
    const float LOG2E = 1.4426950408889634f;
    const float scale2 = 0.17677669529663687f * LOG2E;

    float av = alpha[h];
    float a_sp = (av > 20.f) ? av : log1pf(__expf(av));
    const float a_h = a_sp * LOG2E;

    {
        int r0 = tid >> 2, c = (tid & 3) * 8;
        float knmax = 0.f;
        for (int r = r0; r < kst; r += 64) {
            const ushort_t* src = qkv + ((size_t)(b * kst + r)) * 768 + 256 + h * 32 + c;
            short8 kv = *(const short8*)src;
            short8 vv = *(const short8*)(src + 256);
            *(short8*)&sK[r][c] = kv;
            float ssq = 0.f;
            #pragma unroll
            for (int j = 0; j < 8; ++j) {
                float kf = bf2f(((const ushort_t*)&kv)[j]);
                ssq += kf * kf;
                sVt[c + j][r] = ((const ushort_t*)&vv)[j];
            }
            ssq += __shfl_xor(ssq, 1);
            ssq += __shfl_xor(ssq, 2);
            knmax = fmaxf(knmax, ssq);
        }
        #pragma unroll
        for (int o = 32; o > 0; o >>= 1) knmax = fmaxf(knmax, __shfl_xor(knmax, o));
        if (lane == 0) sRed[w] = knmax;
    }
    __syncthreads();
    const float kmax2 = fmaxf(fmaxf(sRed[0], sRed[1]), fmaxf(sRed[2], sRed[3]));

    for (int qt = w; qt < nqt; qt += 4) {
        const int qb = qt * 16;
        const int qrow = qb + l15;
        short8 qfrag = *(const short8*)(qkv + ((size_t)(b * kst + qrow)) * 768 + h * 32 + quad * 8);
        const f32x4 z = {0.f, 0.f, 0.f, 0.f};

        float qn = 0.f;
        #pragma unroll
        for (int j = 0; j < 8; ++j) { float f = bf2f(qfrag[j]); qn += f * f; }
        qn += __shfl_xor(qn, 16);
        qn += __shfl_xor(qn, 32);
        const float Mr = scale2 * sqrtf(qn * kmax2);
        const float fq = (float)qrow;

        int ch_lo = (qb - 32) >> 5; if (ch_lo < 0) ch_lo = 0;
        int ch_hi = (qb + 47) >> 5;
        const int ch_max = (kst >> 5) - 1;
        if (ch_hi > ch_max) ch_hi = ch_max;

        f32x4 o0 = z, o1 = z;
        float lsum = 0.f;
        for (int ch = ch_lo; ch <= ch_hi; ++ch) {
            const int kb = ch * 32;
            short8 kf0 = *(const short8*)&sK[kb + l15][quad * 8];
            short8 kf1 = *(const short8*)&sK[kb + 16 + l15][quad * 8];
            f32x4 s0 = __builtin_amdgcn_mfma_f32_16x16x32_bf16(kf0, qfrag, z, 0, 0, 0);
            f32x4 s1 = __builtin_amdgcn_mfma_f32_16x16x32_bf16(kf1, qfrag, z, 0, 0, 0);
            float p0[4], p1[4];
            #pragma unroll
            for (int r = 0; r < 4; ++r) {
                int k0 = kb + quad * 4 + r;
                int k1 = k0 + 16;
                float b0 = s0[r] * scale2 - (a_h * fabsf(fq - (float)k0) + Mr);
                float b1 = s1[r] * scale2 - (a_h * fabsf(fq - (float)k1) + Mr);
                p0[r] = exp2f(b0);
                p1[r] = exp2f(b1);
            }
            lsum += (p0[0] + p0[1]) + (p0[2] + p0[3]) + (p1[0] + p1[1]) + (p1[2] + p1[3]);
            unsigned* prow = (unsigned*)&sPT[w][l15][0];
            prow[quad * 2]     = pack2bf(p0[0], p0[1]);
            prow[quad * 2 + 1] = pack2bf(p0[2], p0[3]);
            prow[8 + quad * 2]     = pack2bf(p1[0], p1[1]);
            prow[8 + quad * 2 + 1] = pack2bf(p1[2], p1[3]);
            short8 pB = *(const short8*)&sPT[w][l15][quad * 8];
            short8 v0 = *(const short8*)&sVt[l15][kb + quad * 8];
            short8 v1 = *(const short8*)&sVt[16 + l15][kb + quad * 8];
            o0 = __builtin_amdgcn_mfma_f32_16x16x32_bf16(v0, pB, o0, 0, 0, 0);
            o1 = __builtin_amdgcn_mfma_f32_16x16x32_bf16(v1, pB, o1, 0, 0, 0);
        }
        lsum += __shfl_xor(lsum, 16);
        lsum += __shfl_xor(lsum, 32);

        {
            float inv = 1.f / lsum;
            unsigned* dst = (unsigned*)&O[((size_t)(b * ost + qrow)) * 256 + h * 32 + quad * 4];
            dst[0] = pack2bf(o0[0] * inv, o0[1] * inv);
            dst[1] = pack2bf(o0[2] * inv, o0[3] * inv);
            dst[8] = pack2bf(o1[0] * inv, o1[1] * inv);
            dst[9] = pack2bf(o1[2] * inv, o1[3] * inv);
        }
    }
}

// ---------------- fused head: final LN + cls MLP + logit (1 block/batch) -----
__global__ __launch_bounds__(256) void head_kernel(
    const float* __restrict__ h449,
    const float* __restrict__ fing, const float* __restrict__ finb,
    const ushort_t* __restrict__ cw1T, const float* __restrict__ cb1,
    const float* __restrict__ cw2, const float* __restrict__ b2,
    float* __restrict__ out)
{
    __shared__ float xn[256];
    __shared__ float red[4];
    const int b = blockIdx.x, d = threadIdx.x;
    float v = h449[(size_t)b * TTT * 256 + d];
    float s = v;
    #pragma unroll
    for (int o = 32; o > 0; o >>= 1) s += __shfl_down(s, o, 64);
    if ((d & 63) == 0) red[d >> 6] = s;
    __syncthreads();
    float mean = (red[0] + red[1] + red[2] + red[3]) * (1.f / 256.f);
    __syncthreads();
    float diff = v - mean;
    float s2 = diff * diff;
    #pragma unroll
    for (int o = 32; o > 0; o >>= 1) s2 += __shfl_down(s2, o, 64);
    if ((d & 63) == 0) red[d >> 6] = s2;
    __syncthreads();
    float rstd = rsqrtf((red[0] + red[1] + red[2] + red[3]) * (1.f / 256.f) + 1e-5f);
    xn[d] = diff * rstd * fing[d] + finb[d];
    __syncthreads();
    const ushort_t* wrow = cw1T + (size_t)d * 256;
    float acc = 0.f;
    #pragma unroll 4
    for (int k = 0; k < 256; k += 8) {
        short8 wv = *(const short8*)&wrow[k];
        #pragma unroll
        for (int j = 0; j < 8; ++j) acc += xn[k + j] * bf2f(((const ushort_t*)&wv)[j]);
    }
    float p = gelu_f(acc + cb1[d]) * cw2[d];
    #pragma unroll
    for (int o = 32; o > 0; o >>= 1) p += __shfl_down(p, o, 64);
    __syncthreads();
    if ((d & 63) == 0) red[d >> 6] = p;
    __syncthreads();
    if (d == 0) out[b] = red[0] + red[1] + red[2] + red[3] + b2[0];
}

// ---------------- orchestration ----------------
extern "C" void kernel_launch(void* const* d_in, const int* in_sizes, int n_in,
                              void* d_out, int out_size, void* d_ws, size_t ws_size,
                              hipStream_t stream)
{
    const float* x      = (const float*)d_in[0];
    const float* ipw    = (const float*)d_in[1];
    const float* ipb    = (const float*)d_in[2];
    const float* convw  = (const float*)d_in[3];
    const float* convb  = (const float*)d_in[4];
    const float* bng    = (const float*)d_in[5];
    const float* bnb    = (const float*)d_in[6];
    const float* bnrm   = (const float*)d_in[7];
    const float* bnrv   = (const float*)d_in[8];
    const float* gatew  = (const float*)d_in[9];
    const float* gateb  = (const float*)d_in[10];
    const float* mpw    = (const float*)d_in[11];
    const float* mpb    = (const float*)d_in[12];
    const float* clstok = (const float*)d_in[13];
    const float* qkvw   = (const float*)d_in[14];
    const float* qkvb   = (const float*)d_in[15];
    const float* outw   = (const float*)d_in[16];
    const float* outb   = (const float*)d_in[17];
    const float* alpha  = (const float*)d_in[18];
    const float* ln1g   = (const float*)d_in[19];
    const float* ln1b   = (const float*)d_in[20];
    const float* ln2g   = (const float*)d_in[21];
    const float* ln2b   = (const float*)d_in[22];
    const float* fw1    = (const float*)d_in[23];
    const float* fb1    = (const float*)d_in[24];
    const float* fw2    = (const float*)d_in[25];
    const float* fb2    = (const float*)d_in[26];
    const float* fing   = (const float*)d_in[27];
    const float* finb   = (const float*)d_in[28];
    const float* cw1    = (const float*)d_in[29];
    const float* cb1    = (const float*)d_in[30];
    const float* cw2    = (const float*)d_in[31];
    const float* cb2    = (const float*)d_in[32];

    const int KL[4] = {160, 128, 96, 64};
    const int QL[4] = {128, 96, 64, 16};

    // ---- workspace layout ----
    char* base = (char*)d_ws;
    size_t off = 0;
    auto alloc = [&](size_t bytes) { char* p = base + off; off += (bytes + 255) & ~(size_t)255; return p; };
    float*    h448  = (float*)alloc((size_t)MFRONT * 256 * 4);
    float*    h449  = (float*)alloc((size_t)MPAD * 256 * 4);
    float*    bufA  = (float*)alloc((size_t)MFRONT * 768 * 4);
    ushort_t* conv_bf = (ushort_t*)bufA;
    ushort_t* qkv_bf  = (ushort_t*)bufA;
    ushort_t* bufMid  = (ushort_t*)bufA;
    ushort_t* bufB  = (ushort_t*)alloc((size_t)MFRONT * 256 * 2);
    ushort_t* bufB2 = (ushort_t*)alloc((size_t)MFRONT * 256 * 2);
    ushort_t* bufC  = (ushort_t*)alloc((size_t)64 * 128 * 256 * 2);
    ushort_t* h448g = (ushort_t*)alloc((size_t)BB * GROWS * 256 * 2);
    ushort_t* wrepT = (ushort_t*)alloc((size_t)3 * 256 * 768 * 2);
    ushort_t* ipwT  = (ushort_t*)alloc((size_t)64 * 256 * 2);
    ushort_t* mpwT  = (ushort_t*)alloc((size_t)256 * 256 * 2);
    ushort_t* qkvT  = (ushort_t*)alloc((size_t)4 * 768 * 256 * 2);
    ushort_t* outwT = (ushort_t*)alloc((size_t)4 * 256 * 256 * 2);
    ushort_t* fw1T  = (ushort_t*)alloc((size_t)4 * 1024 * 256 * 2);
    ushort_t* fw2T  = (ushort_t*)alloc((size_t)4 * 256 * 1024 * 2);
    ushort_t* cw1T  = (ushort_t*)alloc((size_t)256 * 256 * 2);
    float*    bnsc  = (float*)alloc(768 * 4);
    float*    bnsh  = (float*)alloc(768 * 4);

    auto gemm = [&](const ushort_t* A, const ushort_t* Bt, void* C, ushort_t* C2,
                    const float* bias, const float* scl, const float* shf, const float* R,
                    int M, int N, int K, int a_dil, int gelu_fl, int omode, int pemode,
                    int rc_mod = 0, int gz = 1) {
        dim3 grid(N / 128, M / 128, gz);
        hipLaunchKernelGGL(gemm_bf16, grid, dim3(256), 0, stream,
                           A, Bt, C, C2, bias, scl, shf, R, M, N, K, a_dil, gelu_fl,
                           omode, pemode, rc_mod);
    };
    auto gemmln = [&](const ushort_t* A, const ushort_t* Bt, float* C, ushort_t* Yp,
                      const float* bias, const float* R,
                      const float* g, const float* b,
                      int M, int K, int pemode, int rcm) {
        hipLaunchKernelGGL(gemm_ln, dim3(1, M / 64), dim3(256), 0, stream,
                           A, Bt, C, Yp, bias, R, g, b, M, K, pemode, rcm);
    };

    // ---- prep: transposes + conv repack + BN + guard zero + cls copy/LN ----
    hipLaunchKernelGGL(prep_all, dim3(3240), dim3(256), 0, stream,
                       ipw, mpw, qkvw, outw, fw1, fw2, cw1,
                       ipwT, mpwT, qkvT, outwT, fw1T, fw2T, cw1T,
                       convw, wrepT, bng, bnb, bnrm, bnrv, bnsc, bnsh,
                       h448g, clstok, h449, ln1g, ln1b, bufB2);

    // ---- input projection on rows t<160: h448 f32 + h448g bf16 (guarded) ----
    gemm((const ushort_t*)x, ipwT, h448, h448g, ipb, nullptr, nullptr, nullptr,
         MFRONT, 256, 64, -2, 0, 2, 0);

    // ---- conv (3 scales in z), DMA staging from h448g, fused gelu+BN ----
    gemm(h448g, wrepT, conv_bf, nullptr, convb, bnsc, bnsh, nullptr,
         MFRONT, 256, 768, -1, 1, 1, 0, 0, 3);
    hipLaunchKernelGGL(gate_fuse, dim3(MFRONT / 4), dim3(256), 0, stream,
                       conv_bf, gatew, gateb, bufB, MFRONT);
    // ms_proj + residual + PE -> h449 rows 1..160; fused LN1(l0) -> bufB2
    gemmln(bufB, mpwT, h449, bufB2, mpb, h448, ln1g, ln1b,
           MFRONT, 256, 1, 0);

    // ---- transformer layers on the shrinking cone ----
    for (int l = 0; l < LAYERS; ++l) {
        const int Kl = KL[l], Ql = QL[l];
        const int MK = 64 * Kl, MQ = 64 * Ql;
        gemm(bufB2, qkvT + (size_t)l * 768 * 256, qkv_bf, nullptr, qkvb + l * 768,
             nullptr, nullptr, nullptr, MK, 768, 256, 0, 0, 1, 0);
        hipLaunchKernelGGL(attn8_kernel, dim3(BB * HEADS), dim3(256), 0, stream,
                           qkv_bf, alpha + l * HEADS, bufC, Kl, Ql / 16, Ql);
        // out-proj + residual -> h449 ; fused LN2(l) -> bufB2
        gemmln(bufC, outwT + (size_t)l * 65536, h449, bufB2, outb + l * 256,
               h449, ln2g + l * 256, ln2b + l * 256, MQ, 256, 0, Ql);
        gemm(bufB2, fw1T + (size_t)l * 262144, bufMid, nullptr, fb1 + l * 1024,
             nullptr, nullptr, nullptr, MQ, 1024, 256, 0, 1, 1, 0);
        // ffn2 + residual -> h449 ; fused LN1(l+1) -> bufB2 (skip on last layer)
        gemmln(bufMid, fw2T + (size_t)l * 262144, h449,
               (l < 3) ? bufB2 : nullptr, fb2 + l * 256, h449,
               (l < 3) ? ln1g + (l + 1) * 256 : nullptr,
               (l < 3) ? ln1b + (l + 1) * 256 : nullptr,
               MQ, 1024, 0, Ql);
    }

    // ---- fused head: final LN + cls MLP + logit ----
    hipLaunchKernelGGL(head_kernel, dim3(BB), dim3(256), 0, stream,
                       h449, fing, finb, cw1T, cb1, cw2, cb2, (float*)d_out);
}